// Round 3
// baseline (493.186 us; speedup 1.0000x reference)
//
#include <hip/hip_runtime.h>
#include <math.h>

namespace {
constexpr int B_ = 2, CIN = 8, H_ = 224, W_ = 224;
constexpr int K_ = 7;
constexpr int F_ = 64, E_ = 8;
constexpr int N1 = 43, N2 = 43, N_ = N1 * N2;   // 1849
constexpr int M_ = 49;                           // candidates per query
constexpr int D_ = 800;                          // patch dim (C*P*P)
constexpr int HW = H_ * W_;

// workspace layout (floats).
constexpr size_t FHW = (size_t)B_ * F_ * HW;     // 6,422,528
constexpr size_t OFF_H1E = 0;                    // channels-last [b][h][w][64]
constexpr size_t OFF_H1T = OFF_H1E + FHW;
constexpr size_t OFF_H2E = OFF_H1T + FHW;        // NCHW
constexpr size_t OFF_H2T = OFF_H2E + FHW;
constexpr size_t OFF_WK  = 0;                                  // B*N*343
constexpr size_t OFF_NB  = 1280000;                            // > Wk end
constexpr size_t OFF_XE  = OFF_H2T + FHW;
constexpr size_t OFF_LTM = OFF_XE + (size_t)B_ * E_ * HW;
constexpr size_t OFF_PE  = OFF_LTM + (size_t)B_ * HW;
constexpr size_t OFF_YP  = OFF_PE + (size_t)B_ * N_ * D_;
constexpr size_t OFF_LT  = OFF_YP + (size_t)B_ * N_ * D_;
constexpr size_t OFF_SQ  = OFF_LT + (size_t)B_ * N_;
// conv2 prepped weights overlap the xe region (consumed by conv2 before
// reduce9 writes xe): 2 buffers x 294912 ushorts = 294,912 floats < 802,816.
constexpr int WPREP_N = 294912;  // 2br * 2kcb * 9idx * 4wv * 64lane * 8j

// conv3 split partials live in the dead h1e/h1t region (conv2 inputs,
// consumed before conv3 runs): 8 * B * 9 * HW = 7,225,344 < 12,845,056.
constexpr int SPL = 8;                            // cin splits for conv3
constexpr int RTOT = B_ * 9 * HW;                 // 903,168 per split

__device__ __forceinline__ int clampi(int v, int lo, int hi) {
  return min(max(v, lo), hi);
}

typedef __attribute__((ext_vector_type(8))) short short8;
typedef __attribute__((ext_vector_type(4))) float float4v;
} // namespace

// ---------------------------------------------------------------------------
// conv1 (8->64, relu), e+t merged (z: bit0=batch, bit1=branch).
// R10: weights read straight from global via wave-uniform indices -> s_load
// (scalar cache), freeing the LDS pipe of 48 broadcast b128 reads per ci.
// LDS store-transpose epilogue kept from R9. Same FMA order -> identical.
// ---------------------------------------------------------------------------
__global__ __launch_bounds__(256) void conv1m_k(
    const float* __restrict__ x,
    const float* __restrict__ w_e, const float* __restrict__ b_e, float* __restrict__ o_e,
    const float* __restrict__ w_t, const float* __restrict__ b_t, float* __restrict__ o_t) {
  constexpr int CI = 8, COG = 16, CIB = 4;
  constexpr int TR = 18, TC = 34;            // padded tile 18 rows x 34 cols
  constexpr int PLN = TR * TC;               // 612
  constexpr int NST = CIB * PLN;             // 2448
  constexpr int NLD = (NST + 255) / 256;     // 10

  const int cog = blockIdx.x;                // 0..3
  const int tile = blockIdx.y;               // 0..97 (14 x 7)
  const int b = blockIdx.z & 1, br = blockIdx.z >> 1;
  const float* wgt = br ? w_t : w_e;
  const float* bias = br ? b_t : b_e;
  float* out = br ? o_t : o_e;
  const int co0 = cog * COG;
  const int th0 = (tile / 7) * 16, tw0 = (tile % 7) * 32;
  const int tid = threadIdx.x;
  const int tx = tid & 31, ty = tid >> 5;    // ty 0..7, 2 rows each

  // unioned LDS: compute phase uses sT (2448 floats); store phase reuses it
  // as a 16x32x17 transpose tile (8704 floats).
  __shared__ float smem[16 * 32 * 17];       // 34816 B
  float* sT = smem;                          // [CIB][PLN]

  int po[NLD];
  unsigned okm = 0;
#pragma unroll
  for (int j = 0; j < NLD; ++j) {
    int s = tid + 256 * j;
    int pl = s / PLN, rem = s - pl * PLN;
    int lr = rem / TC, lc = rem - lr * TC;
    int gh = th0 + lr - 1, gw = tw0 + lc - 1;
    bool ok = (s < NST) && gh >= 0 && gh < H_ && gw >= 0 && gw < W_;
    po[j] = ok ? (pl * HW + gh * W_ + gw) : 0;
    if (ok) okm |= (1u << j);
  }

  const float* inB = x + (size_t)b * CI * HW;
  float stg[NLD];
#pragma unroll
  for (int j = 0; j < NLD; ++j) {
    float v = inB[po[j]];
    stg[j] = ((okm >> j) & 1) ? v : 0.f;
  }

  float acc[COG][2];
#pragma unroll
  for (int c = 0; c < COG; ++c) {
    float bv = bias[co0 + c];
    acc[c][0] = bv;
    acc[c][1] = bv;
  }

  for (int cb = 0; cb < CI; cb += CIB) {
    __syncthreads();
#pragma unroll
    for (int j = 0; j < NLD; ++j) {
      int s = tid + 256 * j;
      if (s < NST) sT[s] = stg[j];
    }
    __syncthreads();
    if (cb + CIB < CI) {
      const float* inN = inB + (size_t)(cb + CIB) * HW;
#pragma unroll
      for (int j = 0; j < NLD; ++j) {
        float v = inN[po[j]];
        stg[j] = ((okm >> j) & 1) ? v : 0.f;
      }
    }
#pragma unroll
    for (int ci = 0; ci < CIB; ++ci) {
      float iv[4][3];
#pragma unroll
      for (int r = 0; r < 4; ++r)
#pragma unroll
        for (int s2 = 0; s2 < 3; ++s2)
          iv[r][s2] = sT[ci * PLN + (2 * ty + r) * TC + tx + s2];
#pragma unroll
      for (int c = 0; c < COG; ++c) {
        // wave-uniform global weight reads -> scalar loads (s_load)
        const float* wp = &wgt[((size_t)(co0 + c) * CI + cb + ci) * 9];
#pragma unroll
        for (int dy = 0; dy < 2; ++dy) {
          acc[c][dy] += iv[dy + 0][0] * wp[0] + iv[dy + 0][1] * wp[1] +
                        iv[dy + 0][2] * wp[2] + iv[dy + 1][0] * wp[3] +
                        iv[dy + 1][1] * wp[4] + iv[dy + 1][2] * wp[5] +
                        iv[dy + 2][0] * wp[6] + iv[dy + 2][1] * wp[7] +
                        iv[dy + 2][2] * wp[8];
        }
      }
    }
  }

  // ---- store-transpose epilogue ----
  __syncthreads();                            // all waves done reading sT
#pragma unroll
  for (int dy = 0; dy < 2; ++dy) {
    int r = 2 * ty + dy;
#pragma unroll
    for (int c = 0; c < COG; ++c)
      smem[(r * 32 + tx) * 17 + c] = fmaxf(acc[c][dy], 0.f);
  }
  __syncthreads();
#pragma unroll
  for (int i = 0; i < 8; ++i) {
    int f = tid + 256 * i;
    int q = f & 3, px = f >> 2;               // px = row*32+col
    int row = px >> 5, col = px & 31;
    float4v v;
#pragma unroll
    for (int e = 0; e < 4; ++e) v[e] = smem[px * 17 + 4 * q + e];
    *(float4v*)&out[(((size_t)b * H_ + th0 + row) * W_ + tw0 + col) * 64 + co0 + 4 * q] = v;
  }
}

// ---------------------------------------------------------------------------
// Weight prep for MFMA conv2 (unchanged).
// ---------------------------------------------------------------------------
__global__ __launch_bounds__(256) void wprep_k(const float* __restrict__ w_e,
                                               const float* __restrict__ w_t,
                                               unsigned short* __restrict__ whi,
                                               unsigned short* __restrict__ wlo) {
  int t = blockIdx.x * 256 + threadIdx.x;
  if (t >= WPREP_N) return;
  int j = t & 7;
  int lane = (t >> 3) & 63;
  int wv = (t >> 9) & 3;
  int t2 = t >> 11;
  int idx = t2 % 9;
  int t3 = t2 / 9;
  int kcb = t3 & 1;
  int br = t3 >> 1;
  const float* wgt = br ? w_t : w_e;
  int co = wv * 16 + (lane & 15);
  int ci = kcb * 32 + 8 * (lane >> 4) + j;
  float v = wgt[((size_t)co * 64 + ci) * 9 + idx];
  unsigned u = __float_as_uint(v);
  unsigned short hi = (unsigned short)(u >> 16);
  float rem = v - __uint_as_float(u & 0xffff0000u);
  unsigned short lo = (unsigned short)(__float_as_uint(rem) >> 16);
  whi[t] = hi;
  wlo[t] = lo;
}

// ---------------------------------------------------------------------------
// conv2 (64->64, relu) via MFMA bf16 3-term hi/lo split (unchanged).
// ---------------------------------------------------------------------------
__global__ __launch_bounds__(256) void conv2_mfma_k(
    const float* __restrict__ in_e, const float* __restrict__ in_t,
    const unsigned short* __restrict__ whi, const unsigned short* __restrict__ wlo,
    const float* __restrict__ b_e, const float* __restrict__ b_t,
    float* __restrict__ out_e, float* __restrict__ out_t) {
  const int tile = blockIdx.x;
  const int b = blockIdx.z & 1;
  const int br = blockIdx.z >> 1;
  const float* in = br ? in_t : in_e;
  const float* bias = br ? b_t : b_e;
  float* out = br ? out_t : out_e;

  const int th0 = (tile / 14) * 16, tw0 = (tile % 14) * 16;
  const int tid = threadIdx.x;
  const int wv = tid >> 6, lane = tid & 63;
  const int q = lane >> 4, n = lane & 15;

  __shared__ unsigned short sT[18 * 18 * 72];
  unsigned* sT32 = (unsigned*)sT;

  float4v acc[16];
#pragma unroll
  for (int pr = 0; pr < 16; ++pr) acc[pr] = (float4v)0.f;

  const float* inB = in + (size_t)b * HW * 64;
  const short8* whi8 = (const short8*)whi;
  const short8* wlo8 = (const short8*)wlo;

  for (int kcb = 0; kcb < 2; ++kcb) {
    __syncthreads();
    for (int jj = 0; jj < 21; ++jj) {
      int s = tid + 256 * jj;
      if (s < 5184) {
        int sp = s >> 4, cp = s & 15;
        int lr = sp / 18, lc = sp - lr * 18;
        int gh = th0 + lr - 1, gw = tw0 + lc - 1;
        float vx = 0.f, vy = 0.f;
        if (gh >= 0 && gh < H_ && gw >= 0 && gw < W_) {
          const float2 vv =
              *(const float2*)&inB[((size_t)gh * W_ + gw) * 64 + kcb * 32 + 2 * cp];
          vx = vv.x; vy = vv.y;
        }
        unsigned u0 = __float_as_uint(vx), u1 = __float_as_uint(vy);
        float r0 = vx - __uint_as_float(u0 & 0xffff0000u);
        float r1 = vy - __uint_as_float(u1 & 0xffff0000u);
        unsigned l0 = __float_as_uint(r0) >> 16, l1 = __float_as_uint(r1) >> 16;
        sT32[sp * 36 + cp] = (u0 >> 16) | ((u1 >> 16) << 16);
        sT32[sp * 36 + 16 + cp] = l0 | (l1 << 16);
      }
    }
    __syncthreads();

    short8 Ah[9], Al[9];
    const int abase = (((br * 2 + kcb) * 9) * 4 + wv) * 64 + lane;
#pragma unroll
    for (int idx = 0; idx < 9; ++idx) {
      Ah[idx] = whi8[abase + idx * 256];
      Al[idx] = wlo8[abase + idx * 256];
    }

#pragma unroll
    for (int r = 0; r < 18; ++r) {
      short8 Bh[3], Bl[3];
#pragma unroll
      for (int kx = 0; kx < 3; ++kx) {
        const unsigned short* p = &sT[(r * 18 + n + kx) * 72 + 8 * q];
        Bh[kx] = *(const short8*)p;
        Bl[kx] = *(const short8*)(p + 32);
      }
#pragma unroll
      for (int ky = 0; ky < 3; ++ky) {
        const int pr = r - ky;
        if (pr >= 0 && pr < 16) {
#pragma unroll
          for (int kx = 0; kx < 3; ++kx) {
            const int idx = ky * 3 + kx;
            acc[pr] = __builtin_amdgcn_mfma_f32_16x16x32_bf16(Ah[idx], Bh[kx], acc[pr], 0, 0, 0);
            acc[pr] = __builtin_amdgcn_mfma_f32_16x16x32_bf16(Al[idx], Bh[kx], acc[pr], 0, 0, 0);
            acc[pr] = __builtin_amdgcn_mfma_f32_16x16x32_bf16(Ah[idx], Bl[kx], acc[pr], 0, 0, 0);
          }
        }
      }
    }
  }

  float4v bv = *(const float4v*)&bias[wv * 16 + 4 * q];
#pragma unroll
  for (int pr = 0; pr < 16; ++pr) {
#pragma unroll
    for (int r = 0; r < 4; ++r) {
      int co = wv * 16 + 4 * q + r;
      float v = fmaxf(acc[pr][r] + bv[r], 0.f);
      out[((size_t)b * 64 + co) * HW + (th0 + pr) * W_ + tw0 + n] = v;
    }
  }
}

// ---------------------------------------------------------------------------
// conv3 e+t merged, R10: cin split 8 ways (grid z), 32x32 tile, 4 rows/thread,
// CIB=2, weights via wave-uniform global reads (s_load). Each split writes a
// partial [sp][b][9][HW] into the dead h1 region; reduce9_k sums them.
// ---------------------------------------------------------------------------
__global__ __launch_bounds__(256) void conv3s_k(
    const float* __restrict__ h2e, const float* __restrict__ h2t,
    const float* __restrict__ w3e, const float* __restrict__ w3t,
    const float* __restrict__ b3e, const float* __restrict__ b3t,
    float* __restrict__ part) {
  constexpr int CIB = 2;
  constexpr int TR = 34, TC = 34;             // padded tile 34 x 34
  constexpr int PLN = TR * TC;                // 1156
  constexpr int NST = 2 * CIB * PLN;          // 4624 (both branches)
  constexpr int NLD = (NST + 255) / 256;      // 19

  const int tile = blockIdx.x;                // 0..48 (7 x 7)
  const int b = blockIdx.y;
  const int sp = blockIdx.z;                  // cin split 0..7
  const int cin0 = sp * 8;
  const int th0 = (tile / 7) * 32, tw0 = (tile % 7) * 32;
  const int tid = threadIdx.x;
  const int tx = tid & 31, ty = tid >> 5;     // 4 rows per thread

  __shared__ float sT[2][CIB][PLN];           // 18496 B

  int po[NLD];
  unsigned okm = 0;
#pragma unroll
  for (int j = 0; j < NLD; ++j) {
    int s = tid + 256 * j;
    int rem2 = s % (CIB * PLN);
    int pl = rem2 / PLN, rem = rem2 % PLN;
    int lr = rem / TC, lc = rem - lr * TC;
    int gh = th0 + lr - 1, gw = tw0 + lc - 1;
    bool ok = (s < NST) && gh >= 0 && gh < H_ && gw >= 0 && gw < W_;
    po[j] = ok ? (pl * HW + gh * W_ + gw) : 0;
    if (ok) okm |= (1u << j);
  }

  const float* heB = h2e + ((size_t)b * 64 + cin0) * HW;
  const float* htB = h2t + ((size_t)b * 64 + cin0) * HW;

  float stg[NLD];
#pragma unroll
  for (int j = 0; j < NLD; ++j) {
    int s = tid + 256 * j;
    const float* src = (s < CIB * PLN) ? heB : htB;
    float v = src[po[j]];
    stg[j] = ((okm >> j) & 1) ? v : 0.f;
  }

  float acc[9][4];
#pragma unroll
  for (int c = 0; c < 9; ++c) {
    float bv = (sp == 0) ? ((c < 8) ? b3e[c] : b3t[0]) : 0.f;
#pragma unroll
    for (int dy = 0; dy < 4; ++dy) acc[c][dy] = bv;
  }

  for (int cb = 0; cb < 8; cb += CIB) {
    __syncthreads();
#pragma unroll
    for (int j = 0; j < NLD; ++j) {
      int s = tid + 256 * j;
      if (s < NST) ((float*)sT)[s] = stg[j];
    }
    __syncthreads();
    if (cb + CIB < 8) {
      const size_t off = (size_t)(cb + CIB) * HW;
#pragma unroll
      for (int j = 0; j < NLD; ++j) {
        int s = tid + 256 * j;
        const float* src = (s < CIB * PLN) ? (heB + off) : (htB + off);
        float v = src[po[j]];
        stg[j] = ((okm >> j) & 1) ? v : 0.f;
      }
    }
#pragma unroll
    for (int ci = 0; ci < CIB; ++ci) {
      const int cin = cin0 + cb + ci;
      float ive[6][3], ivt[6][3];
#pragma unroll
      for (int r = 0; r < 6; ++r)
#pragma unroll
        for (int s2 = 0; s2 < 3; ++s2) {
          ive[r][s2] = sT[0][ci][(4 * ty + r) * TC + tx + s2];
          ivt[r][s2] = sT[1][ci][(4 * ty + r) * TC + tx + s2];
        }
#pragma unroll
      for (int c = 0; c < 9; ++c) {
        // wave-uniform global weight reads -> scalar loads
        const float* wp = (c < 8) ? &w3e[((size_t)c * 64 + cin) * 9]
                                  : &w3t[(size_t)cin * 9];
        const float (*iv)[3] = (c < 8) ? ive : ivt;
#pragma unroll
        for (int dy = 0; dy < 4; ++dy) {
          acc[c][dy] += iv[dy + 0][0] * wp[0] + iv[dy + 0][1] * wp[1] +
                        iv[dy + 0][2] * wp[2] + iv[dy + 1][0] * wp[3] +
                        iv[dy + 1][1] * wp[4] + iv[dy + 1][2] * wp[5] +
                        iv[dy + 2][0] * wp[6] + iv[dy + 2][1] * wp[7] +
                        iv[dy + 2][2] * wp[8];
        }
      }
    }
  }

  float* pB = part + (size_t)sp * RTOT + (size_t)b * 9 * HW;
#pragma unroll
  for (int dy = 0; dy < 4; ++dy) {
    const int h = th0 + 4 * ty + dy, w = tw0 + tx;
#pragma unroll
    for (int c = 0; c < 9; ++c)
      pB[(size_t)c * HW + h * W_ + w] = acc[c][dy];
  }
}

// ---------------------------------------------------------------------------
// reduce the 8 conv3 partials into xe (c<8) and ltm (c==8).
// ---------------------------------------------------------------------------
__global__ __launch_bounds__(256) void reduce9_k(const float* __restrict__ part,
                                                 float* __restrict__ xe,
                                                 float* __restrict__ ltm) {
  int i = blockIdx.x * 256 + threadIdx.x;
  if (i >= RTOT) return;
  float s = 0.f;
#pragma unroll
  for (int sp = 0; sp < SPL; ++sp) s += part[(size_t)sp * RTOT + i];
  int p = i % HW;
  int c = (i / HW) % 9;
  int b = i / (9 * HW);
  if (c < 8)
    xe[((size_t)(b * 8 + c)) * HW + p] = s;
  else
    ltm[(size_t)b * HW + p] = s;
}

// ---------------------------------------------------------------------------
// prep: per (b,n) block (256 thr): write pe row (from xe), yp row (from x),
// reduce sq = ||pe||^2 and lt = mean of 10x10 ltm patch. (unchanged)
// ---------------------------------------------------------------------------
__global__ __launch_bounds__(256) void prep_k(const float* __restrict__ xe,
                                              const float* __restrict__ x,
                                              const float* __restrict__ ltm,
                                              float* __restrict__ pe,
                                              float* __restrict__ yp,
                                              float* __restrict__ lt,
                                              float* __restrict__ sq) {
  const int n = blockIdx.x, b = blockIdx.y;
  const int tid = threadIdx.x;
  const int wv = tid >> 6, lane = tid & 63;
  const int q1 = n / N2, q2 = n % N2;
  const int r0 = q1 * 5, c0 = q2 * 5;

  float s = 0.f;
  float* peR = pe + ((size_t)b * N_ + n) * D_;
  float* ypR = yp + ((size_t)b * N_ + n) * D_;
#pragma unroll
  for (int j = 0; j < 4; ++j) {
    int d = tid + 256 * j;
    if (d < D_) {
      int c = d / 100;
      int rr = (d / 10) % 10;
      int cc = d % 10;
      size_t si = ((size_t)(b * 8 + c) * H_ + r0 + rr) * W_ + c0 + cc;
      float ve = xe[si];
      float vx = x[si];
      peR[d] = ve;
      ypR[d] = vx;
      s += ve * ve;
    }
  }
  float t = 0.f;
  if (tid < 100) t = ltm[(size_t)b * HW + (r0 + tid / 10) * W_ + c0 + tid % 10];

#pragma unroll
  for (int off = 32; off > 0; off >>= 1) {
    s += __shfl_xor(s, off);
    t += __shfl_xor(t, off);
  }
  __shared__ float rs[4], rt[4];
  if (lane == 0) { rs[wv] = s; rt[wv] = t; }
  __syncthreads();
  if (tid == 0) {
    sq[b * N_ + n] = rs[0] + rs[1] + rs[2] + rs[3];
    lt[b * N_ + n] = (rt[0] + rt[1] + rt[2] + rt[3]) * 0.01f;
  }
}

// ---------------------------------------------------------------------------
// attn stage 1 (unchanged).
// ---------------------------------------------------------------------------
__global__ __launch_bounds__(256) void attn_w_k(const float* __restrict__ pe,
                                                const float* __restrict__ lt,
                                                const float* __restrict__ sq,
                                                float* __restrict__ wk) {
  const int wv = threadIdx.x >> 6, lane = threadIdx.x & 63;
  const int n = blockIdx.x * 4 + wv;
  if (n >= N_) return;
  const int b = blockIdx.y;
  const int q1 = n / N2, q2 = n % N2;

  const float* peB = pe + (size_t)b * N_ * D_;
  const float* qrow = peB + (size_t)n * D_;
  float q[13];
#pragma unroll
  for (int t = 0; t < 13; ++t) {
    int s = t * 64 + lane;
    q[t] = (s < D_) ? qrow[s] : 0.f;
  }

  const float sqn = sq[b * N_ + n];
  const float itemp = expf(-lt[b * N_ + n]);
  float gm = -INFINITY;

  for (int o1 = 0; o1 < 7; ++o1) {
    int c1 = clampi(q1 + o1 - 3, 0, N1 - 1);
    const float* rowb = peB + (size_t)(c1 * N2) * D_;
#pragma unroll
    for (int o2 = 0; o2 < 7; ++o2) {
      int c2 = clampi(q2 + o2 - 3, 0, N2 - 1);
      int cn = c1 * N2 + c2;
      const float* crow = rowb + (size_t)c2 * D_;
      float a = 0.f;
#pragma unroll
      for (int t = 0; t < 13; ++t) {
        float v;
        if (t < 12) v = crow[t * 64 + lane];
        else v = (lane < 32) ? crow[768 + lane] : 0.f;
        a += q[t] * v;
      }
#pragma unroll
      for (int off = 32; off > 0; off >>= 1) a += __shfl_xor(a, off);
      float Dv = -(sqn + sq[b * N_ + cn] - 2.f * a);
      float lg = (cn == n) ? -1e9f : Dv * itemp;
      const int m = o1 * 7 + o2;
      gm = (lane == m) ? lg : gm;
    }
  }

  float cur = (lane < M_) ? gm : -INFINITY;
  float* wrow = wk + (size_t)(b * N_ + n) * (M_ * K_);
#pragma unroll
  for (int k = 0; k < K_; ++k) {
    float mx = cur;
#pragma unroll
    for (int off = 32; off > 0; off >>= 1) mx = fmaxf(mx, __shfl_xor(mx, off));
    float e = (lane < M_) ? expf(cur - mx) : 0.f;
    float ssum = e;
#pragma unroll
    for (int off = 32; off > 0; off >>= 1) ssum += __shfl_xor(ssum, off);
    float w = e / ssum;
    if (lane < M_) wrow[lane * K_ + k] = w;
    cur += log1pf(-fminf(w, 1.f - 1e-6f));
  }
}

// ---------------------------------------------------------------------------
// attn stage 2 (unchanged).
// ---------------------------------------------------------------------------
__global__ __launch_bounds__(256) void attn_pv_k(const float* __restrict__ yp,
                                                 const float* __restrict__ wk,
                                                 float* __restrict__ nb) {
  const int wv = threadIdx.x >> 6, lane = threadIdx.x & 63;
  const int n = blockIdx.x;
  const int b = blockIdx.z;
  const int sl = blockIdx.y * 4 + wv;
  const int d = sl * 64 + lane;
  if (d >= D_) return;
  const int q1 = n / N2, q2 = n % N2;

  const float* ypB = yp + (size_t)b * N_ * D_;
  const float* wrow = wk + (size_t)(b * N_ + n) * (M_ * K_);

  float acc[K_];
#pragma unroll
  for (int k = 0; k < K_; ++k) acc[k] = 0.f;

#pragma unroll
  for (int o1 = 0; o1 < 7; ++o1) {
    int c1 = clampi(q1 + o1 - 3, 0, N1 - 1);
#pragma unroll
    for (int o2 = 0; o2 < 7; ++o2) {
      int c2 = clampi(q2 + o2 - 3, 0, N2 - 1);
      int cn = c1 * N2 + c2;
      float y = ypB[(size_t)cn * D_ + d];
      const int m = o1 * 7 + o2;
#pragma unroll
      for (int k = 0; k < K_; ++k) acc[k] += wrow[m * K_ + k] * y;
    }
  }
#pragma unroll
  for (int k = 0; k < K_; ++k)
    nb[(((size_t)k * B_ + b) * N_ + n) * D_ + d] = acc[k];
}

// ---------------------------------------------------------------------------
// Fused output: channels 0..7 copy x; channels 8..63 fold-gather from nb.
// ---------------------------------------------------------------------------
__global__ __launch_bounds__(256) void foldcopy_k(const float* __restrict__ x,
                                                  const float* __restrict__ nb,
                                                  float* __restrict__ out) {
  int i = blockIdx.x * 256 + threadIdx.x;
  constexpr int CT = CIN * (K_ + 1);  // 64
  constexpr int TOT = B_ * CT * HW;
  if (i >= TOT) return;
  int w = i % W_;
  int h = (i / W_) % H_;
  int c64 = (i / HW) % CT;
  int b = i / (HW * CT);
  if (c64 < CIN) {
    out[i] = x[((size_t)b * CIN + c64) * HW + h * W_ + w];
    return;
  }
  int k = (c64 - CIN) >> 3, c = (c64 - CIN) & 7;
  int q1lo = max(0, (h - 5) / 5), q1hi = min(N1 - 1, h / 5);
  int q2lo = max(0, (w - 5) / 5), q2hi = min(N2 - 1, w / 5);
  float val = 0.f;
  int cnt = 0;
  for (int q1 = q1lo; q1 <= q1hi; ++q1)
    for (int q2 = q2lo; q2 <= q2hi; ++q2) {
      int i0 = h - 5 * q1, j0 = w - 5 * q2;
      int nn = q1 * N2 + q2;
      val += nb[(((size_t)k * B_ + b) * N_ + nn) * D_ + c * 100 + i0 * 10 + j0];
      ++cnt;
    }
  out[i] = (cnt > 0) ? val / (float)cnt : 0.f;
}

extern "C" void kernel_launch(void* const* d_in, const int* in_sizes, int n_in,
                              void* d_out, int out_size, void* d_ws,
                              size_t ws_size, hipStream_t stream) {
  const float* x   = (const float*)d_in[0];
  const float* w1e = (const float*)d_in[1];
  const float* b1e = (const float*)d_in[2];
  const float* w2e = (const float*)d_in[3];
  const float* b2e = (const float*)d_in[4];
  const float* w3e = (const float*)d_in[5];
  const float* b3e = (const float*)d_in[6];
  const float* w1t = (const float*)d_in[7];
  const float* b1t = (const float*)d_in[8];
  const float* w2t = (const float*)d_in[9];
  const float* b2t = (const float*)d_in[10];
  const float* w3t = (const float*)d_in[11];
  const float* b3t = (const float*)d_in[12];

  float* ws  = (float*)d_ws;
  float* out = (float*)d_out;

  float* h1e = ws + OFF_H1E;   // channels-last
  float* h1t = ws + OFF_H1T;   // channels-last
  float* h2e = ws + OFF_H2E;   // NCHW
  float* h2t = ws + OFF_H2T;   // NCHW
  float* wkb = ws + OFF_WK;
  float* nb  = ws + OFF_NB;
  float* xe  = ws + OFF_XE;
  float* ltm = ws + OFF_LTM;
  float* pe  = ws + OFF_PE;
  float* yp  = ws + OFF_YP;
  float* lt  = ws + OFF_LT;
  float* sqv = ws + OFF_SQ;
  unsigned short* whi = (unsigned short*)(ws + OFF_XE);  // consumed before xe written
  unsigned short* wlo = whi + WPREP_N;
  float* part = ws + OFF_H1E;  // conv3 partials over dead h1 region

  // conv2 weight prep
  wprep_k<<<(WPREP_N + 255) / 256, 256, 0, stream>>>(w2e, w2t, whi, wlo);
  // conv1 (8 -> 64, relu), e+t in one dispatch, channels-last output
  conv1m_k<<<dim3(4, 98, 4), 256, 0, stream>>>(x, w1e, b1e, h1e, w1t, b1t, h1t);
  // conv2 (64 -> 64, relu) via MFMA, both branches + batches in one dispatch
  conv2_mfma_k<<<dim3(196, 1, 4), 256, 0, stream>>>(h1e, h1t, whi, wlo, b2e, b2t, h2e, h2t);
  // conv3 (64 -> 8 + 64 -> 1) merged, cin split 8 ways -> 784 blocks
  conv3s_k<<<dim3(49, B_, SPL), 256, 0, stream>>>(h2e, h2t, w3e, w3t, b3e, b3t, part);
  // sum partials into xe / ltm
  reduce9_k<<<(RTOT + 255) / 256, 256, 0, stream>>>(part, xe, ltm);
  // patches + norms + log-temp means fused
  prep_k<<<dim3(N_, B_), 256, 0, stream>>>(xe, x, ltm, pe, yp, lt, sqv);
  // attention stage 1: weights
  attn_w_k<<<dim3((N_ + 3) / 4, B_), 256, 0, stream>>>(pe, lt, sqv, wkb);
  // attention stage 2: weighted neighbor sums
  attn_pv_k<<<dim3(N_, 4, B_), 256, 0, stream>>>(yp, wkb, nb);
  // fused fold + x passthrough
  constexpr int FT = B_ * CIN * (K_ + 1) * HW;
  foldcopy_k<<<(FT + 255) / 256, 256, 0, stream>>>(x, nb, out);
}

// Round 4
// 413.555 us; speedup vs baseline: 1.1926x; 1.1926x over previous
//
#include <hip/hip_runtime.h>
#include <math.h>

namespace {
constexpr int B_ = 2, CIN = 8, H_ = 224, W_ = 224;
constexpr int K_ = 7;
constexpr int F_ = 64, E_ = 8;
constexpr int N1 = 43, N2 = 43, N_ = N1 * N2;   // 1849
constexpr int M_ = 49;                           // candidates per query
constexpr int D_ = 800;                          // patch dim (C*P*P)
constexpr int HW = H_ * W_;

// workspace layout (floats).
constexpr size_t FHW = (size_t)B_ * F_ * HW;     // 6,422,528
constexpr size_t OFF_H1E = 0;                    // channels-last [b][h][w][64]
constexpr size_t OFF_H1T = OFF_H1E + FHW;
constexpr size_t OFF_H2E = OFF_H1T + FHW;        // NCHW
constexpr size_t OFF_H2T = OFF_H2E + FHW;
constexpr size_t OFF_WK  = 0;                                  // B*N*343
constexpr size_t OFF_NB  = 1280000;                            // > Wk end
constexpr size_t OFF_XE  = OFF_H2T + FHW;
constexpr size_t OFF_LTM = OFF_XE + (size_t)B_ * E_ * HW;
constexpr size_t OFF_PE  = OFF_LTM + (size_t)B_ * HW;
constexpr size_t OFF_YP  = OFF_PE + (size_t)B_ * N_ * D_;
constexpr size_t OFF_LT  = OFF_YP + (size_t)B_ * N_ * D_;
constexpr size_t OFF_SQ  = OFF_LT + (size_t)B_ * N_;
// conv2 prepped weights overlap the xe region (consumed by conv2 before
// reduce9 writes xe): 2 buffers x 294912 ushorts = 294,912 floats < 802,816.
constexpr int WPREP_N = 294912;  // 2br * 2kcb * 9idx * 4wv * 64lane * 8j

// conv3 split partials live in the dead h1e/h1t region (conv2 inputs,
// consumed before conv3 runs): 8 * B * 9 * HW = 7,225,344 < 12,845,056.
constexpr int SPL = 8;                            // cin splits for conv3
constexpr int RTOT = B_ * 9 * HW;                 // 903,168 per split

__device__ __forceinline__ int clampi(int v, int lo, int hi) {
  return min(max(v, lo), hi);
}

typedef __attribute__((ext_vector_type(8))) short short8;
typedef __attribute__((ext_vector_type(4))) float float4v;
} // namespace

// ---------------------------------------------------------------------------
// conv1 (8->64, relu), e+t merged (z: bit0=batch, bit1=branch).
// R11: revert weights to LDS (R10's s_load regressed: SGPR-starved k$ reload
// chain); 32x32 tile, 4 rows/thread -> 2x better weight-broadcast
// amortization (48 b128/ci now feed 576 FMA not 288). CIB=2 staging keeps
// VGPR ~130. Store-transpose epilogue in two 16-row halves (LDS union
// 34.8KB -> 4 blocks/CU LDS-wise). Same per-output FMA order -> identical.
// ---------------------------------------------------------------------------
__global__ __launch_bounds__(256) void conv1m_k(
    const float* __restrict__ x,
    const float* __restrict__ w_e, const float* __restrict__ b_e, float* __restrict__ o_e,
    const float* __restrict__ w_t, const float* __restrict__ b_t, float* __restrict__ o_t) {
  constexpr int CI = 8, COG = 16, CIB = 2;
  constexpr int TR = 34, TC = 34;            // padded tile 34 x 34
  constexpr int PLN = TR * TC;               // 1156
  constexpr int NST = CIB * PLN;             // 2312
  constexpr int NLD = (NST + 255) / 256;     // 10

  const int cog = blockIdx.x;                // 0..3
  const int tile = blockIdx.y;               // 0..48 (7 x 7)
  const int b = blockIdx.z & 1, br = blockIdx.z >> 1;
  const float* wgt = br ? w_t : w_e;
  const float* bias = br ? b_t : b_e;
  float* out = br ? o_t : o_e;
  const int co0 = cog * COG;
  const int th0 = (tile / 7) * 32, tw0 = (tile % 7) * 32;
  const int tid = threadIdx.x;
  const int tx = tid & 31, ty = tid >> 5;    // ty 0..7, 4 rows each

  // unioned LDS: compute phase uses sW (1536) + sT (2312) = 3848 floats;
  // store phase reuses it as a 16x32x17 transpose tile (8704 floats).
  __shared__ float smem[16 * 32 * 17];       // 34816 B
  float* sW = smem;                          // [COG*CI*12]
  float* sT = smem + COG * CI * 12;          // [CIB][PLN]

  for (int s = tid; s < COG * CI * 12; s += 256) {
    int c = s / (CI * 12);
    int rem = s - c * (CI * 12);
    int ci = rem / 12, r = rem - ci * 12;
    sW[s] = (r < 9) ? wgt[((size_t)(co0 + c) * CI + ci) * 9 + r] : 0.f;
  }

  int po[NLD];
  unsigned okm = 0;
#pragma unroll
  for (int j = 0; j < NLD; ++j) {
    int s = tid + 256 * j;
    int pl = s / PLN, rem = s - pl * PLN;
    int lr = rem / TC, lc = rem - lr * TC;
    int gh = th0 + lr - 1, gw = tw0 + lc - 1;
    bool ok = (s < NST) && gh >= 0 && gh < H_ && gw >= 0 && gw < W_;
    po[j] = ok ? (pl * HW + gh * W_ + gw) : 0;
    if (ok) okm |= (1u << j);
  }

  const float* inB = x + (size_t)b * CI * HW;
  float stg[NLD];
#pragma unroll
  for (int j = 0; j < NLD; ++j) {
    float v = inB[po[j]];
    stg[j] = ((okm >> j) & 1) ? v : 0.f;
  }

  float acc[COG][4];
#pragma unroll
  for (int c = 0; c < COG; ++c) {
    float bv = bias[co0 + c];
#pragma unroll
    for (int dy = 0; dy < 4; ++dy) acc[c][dy] = bv;
  }

  for (int cb = 0; cb < CI; cb += CIB) {
    __syncthreads();
#pragma unroll
    for (int j = 0; j < NLD; ++j) {
      int s = tid + 256 * j;
      if (s < NST) sT[s] = stg[j];
    }
    __syncthreads();
    if (cb + CIB < CI) {
      const float* inN = inB + (size_t)(cb + CIB) * HW;
#pragma unroll
      for (int j = 0; j < NLD; ++j) {
        float v = inN[po[j]];
        stg[j] = ((okm >> j) & 1) ? v : 0.f;
      }
    }
#pragma unroll
    for (int ci = 0; ci < CIB; ++ci) {
      float iv[6][3];
#pragma unroll
      for (int r = 0; r < 6; ++r)
#pragma unroll
        for (int s2 = 0; s2 < 3; ++s2)
          iv[r][s2] = sT[ci * PLN + (4 * ty + r) * TC + tx + s2];
#pragma unroll
      for (int c = 0; c < COG; ++c) {
        const float4* wp = (const float4*)&sW[(c * CI + cb + ci) * 12];
        float4 wa = wp[0], wb = wp[1], wc = wp[2];
#pragma unroll
        for (int dy = 0; dy < 4; ++dy) {
          acc[c][dy] += iv[dy + 0][0] * wa.x + iv[dy + 0][1] * wa.y +
                        iv[dy + 0][2] * wa.z + iv[dy + 1][0] * wa.w +
                        iv[dy + 1][1] * wb.x + iv[dy + 1][2] * wb.y +
                        iv[dy + 2][0] * wb.z + iv[dy + 2][1] * wb.w +
                        iv[dy + 2][2] * wc.x;
        }
      }
    }
  }

  // ---- store-transpose epilogue, two 16-row halves ----
#pragma unroll
  for (int hf = 0; hf < 2; ++hf) {
    __syncthreads();
    if ((ty >> 2) == hf) {
#pragma unroll
      for (int dy = 0; dy < 4; ++dy) {
        int lr = 4 * (ty & 3) + dy;          // local row 0..15
#pragma unroll
        for (int c = 0; c < COG; ++c)
          smem[(lr * 32 + tx) * 17 + c] = fmaxf(acc[c][dy], 0.f);
      }
    }
    __syncthreads();
#pragma unroll
    for (int i = 0; i < 8; ++i) {
      int f = tid + 256 * i;
      int q = f & 3, px = f >> 2;             // px = lr*32+col
      int lr = px >> 5, col = px & 31;
      float4v v;
#pragma unroll
      for (int e = 0; e < 4; ++e) v[e] = smem[px * 17 + 4 * q + e];
      *(float4v*)&out[(((size_t)b * H_ + th0 + 16 * hf + lr) * W_ + tw0 + col) * 64 +
                      co0 + 4 * q] = v;
    }
  }
}

// ---------------------------------------------------------------------------
// Weight prep for MFMA conv2 (unchanged).
// ---------------------------------------------------------------------------
__global__ __launch_bounds__(256) void wprep_k(const float* __restrict__ w_e,
                                               const float* __restrict__ w_t,
                                               unsigned short* __restrict__ whi,
                                               unsigned short* __restrict__ wlo) {
  int t = blockIdx.x * 256 + threadIdx.x;
  if (t >= WPREP_N) return;
  int j = t & 7;
  int lane = (t >> 3) & 63;
  int wv = (t >> 9) & 3;
  int t2 = t >> 11;
  int idx = t2 % 9;
  int t3 = t2 / 9;
  int kcb = t3 & 1;
  int br = t3 >> 1;
  const float* wgt = br ? w_t : w_e;
  int co = wv * 16 + (lane & 15);
  int ci = kcb * 32 + 8 * (lane >> 4) + j;
  float v = wgt[((size_t)co * 64 + ci) * 9 + idx];
  unsigned u = __float_as_uint(v);
  unsigned short hi = (unsigned short)(u >> 16);
  float rem = v - __uint_as_float(u & 0xffff0000u);
  unsigned short lo = (unsigned short)(__float_as_uint(rem) >> 16);
  whi[t] = hi;
  wlo[t] = lo;
}

// ---------------------------------------------------------------------------
// conv2 (64->64, relu) via MFMA bf16 3-term hi/lo split (unchanged).
// ---------------------------------------------------------------------------
__global__ __launch_bounds__(256) void conv2_mfma_k(
    const float* __restrict__ in_e, const float* __restrict__ in_t,
    const unsigned short* __restrict__ whi, const unsigned short* __restrict__ wlo,
    const float* __restrict__ b_e, const float* __restrict__ b_t,
    float* __restrict__ out_e, float* __restrict__ out_t) {
  const int tile = blockIdx.x;
  const int b = blockIdx.z & 1;
  const int br = blockIdx.z >> 1;
  const float* in = br ? in_t : in_e;
  const float* bias = br ? b_t : b_e;
  float* out = br ? out_t : out_e;

  const int th0 = (tile / 14) * 16, tw0 = (tile % 14) * 16;
  const int tid = threadIdx.x;
  const int wv = tid >> 6, lane = tid & 63;
  const int q = lane >> 4, n = lane & 15;

  __shared__ unsigned short sT[18 * 18 * 72];
  unsigned* sT32 = (unsigned*)sT;

  float4v acc[16];
#pragma unroll
  for (int pr = 0; pr < 16; ++pr) acc[pr] = (float4v)0.f;

  const float* inB = in + (size_t)b * HW * 64;
  const short8* whi8 = (const short8*)whi;
  const short8* wlo8 = (const short8*)wlo;

  for (int kcb = 0; kcb < 2; ++kcb) {
    __syncthreads();
    for (int jj = 0; jj < 21; ++jj) {
      int s = tid + 256 * jj;
      if (s < 5184) {
        int sp = s >> 4, cp = s & 15;
        int lr = sp / 18, lc = sp - lr * 18;
        int gh = th0 + lr - 1, gw = tw0 + lc - 1;
        float vx = 0.f, vy = 0.f;
        if (gh >= 0 && gh < H_ && gw >= 0 && gw < W_) {
          const float2 vv =
              *(const float2*)&inB[((size_t)gh * W_ + gw) * 64 + kcb * 32 + 2 * cp];
          vx = vv.x; vy = vv.y;
        }
        unsigned u0 = __float_as_uint(vx), u1 = __float_as_uint(vy);
        float r0 = vx - __uint_as_float(u0 & 0xffff0000u);
        float r1 = vy - __uint_as_float(u1 & 0xffff0000u);
        unsigned l0 = __float_as_uint(r0) >> 16, l1 = __float_as_uint(r1) >> 16;
        sT32[sp * 36 + cp] = (u0 >> 16) | ((u1 >> 16) << 16);
        sT32[sp * 36 + 16 + cp] = l0 | (l1 << 16);
      }
    }
    __syncthreads();

    short8 Ah[9], Al[9];
    const int abase = (((br * 2 + kcb) * 9) * 4 + wv) * 64 + lane;
#pragma unroll
    for (int idx = 0; idx < 9; ++idx) {
      Ah[idx] = whi8[abase + idx * 256];
      Al[idx] = wlo8[abase + idx * 256];
    }

#pragma unroll
    for (int r = 0; r < 18; ++r) {
      short8 Bh[3], Bl[3];
#pragma unroll
      for (int kx = 0; kx < 3; ++kx) {
        const unsigned short* p = &sT[(r * 18 + n + kx) * 72 + 8 * q];
        Bh[kx] = *(const short8*)p;
        Bl[kx] = *(const short8*)(p + 32);
      }
#pragma unroll
      for (int ky = 0; ky < 3; ++ky) {
        const int pr = r - ky;
        if (pr >= 0 && pr < 16) {
#pragma unroll
          for (int kx = 0; kx < 3; ++kx) {
            const int idx = ky * 3 + kx;
            acc[pr] = __builtin_amdgcn_mfma_f32_16x16x32_bf16(Ah[idx], Bh[kx], acc[pr], 0, 0, 0);
            acc[pr] = __builtin_amdgcn_mfma_f32_16x16x32_bf16(Al[idx], Bh[kx], acc[pr], 0, 0, 0);
            acc[pr] = __builtin_amdgcn_mfma_f32_16x16x32_bf16(Ah[idx], Bl[kx], acc[pr], 0, 0, 0);
          }
        }
      }
    }
  }

  float4v bv = *(const float4v*)&bias[wv * 16 + 4 * q];
#pragma unroll
  for (int pr = 0; pr < 16; ++pr) {
#pragma unroll
    for (int r = 0; r < 4; ++r) {
      int co = wv * 16 + 4 * q + r;
      float v = fmaxf(acc[pr][r] + bv[r], 0.f);
      out[((size_t)b * 64 + co) * HW + (th0 + pr) * W_ + tw0 + n] = v;
    }
  }
}

// ---------------------------------------------------------------------------
// conv3 e+t merged, cin split 8 ways (grid z), 32x32 tile, 4 rows/thread,
// CIB=2, weights via wave-uniform global reads. (unchanged from R10 — it
// left the top-5.) Partials [sp][b][9][HW] in dead h1 region.
// ---------------------------------------------------------------------------
__global__ __launch_bounds__(256) void conv3s_k(
    const float* __restrict__ h2e, const float* __restrict__ h2t,
    const float* __restrict__ w3e, const float* __restrict__ w3t,
    const float* __restrict__ b3e, const float* __restrict__ b3t,
    float* __restrict__ part) {
  constexpr int CIB = 2;
  constexpr int TR = 34, TC = 34;             // padded tile 34 x 34
  constexpr int PLN = TR * TC;                // 1156
  constexpr int NST = 2 * CIB * PLN;          // 4624 (both branches)
  constexpr int NLD = (NST + 255) / 256;      // 19

  const int tile = blockIdx.x;                // 0..48 (7 x 7)
  const int b = blockIdx.y;
  const int sp = blockIdx.z;                  // cin split 0..7
  const int cin0 = sp * 8;
  const int th0 = (tile / 7) * 32, tw0 = (tile % 7) * 32;
  const int tid = threadIdx.x;
  const int tx = tid & 31, ty = tid >> 5;     // 4 rows per thread

  __shared__ float sT[2][CIB][PLN];           // 18496 B

  int po[NLD];
  unsigned okm = 0;
#pragma unroll
  for (int j = 0; j < NLD; ++j) {
    int s = tid + 256 * j;
    int rem2 = s % (CIB * PLN);
    int pl = rem2 / PLN, rem = rem2 % PLN;
    int lr = rem / TC, lc = rem - lr * TC;
    int gh = th0 + lr - 1, gw = tw0 + lc - 1;
    bool ok = (s < NST) && gh >= 0 && gh < H_ && gw >= 0 && gw < W_;
    po[j] = ok ? (pl * HW + gh * W_ + gw) : 0;
    if (ok) okm |= (1u << j);
  }

  const float* heB = h2e + ((size_t)b * 64 + cin0) * HW;
  const float* htB = h2t + ((size_t)b * 64 + cin0) * HW;

  float stg[NLD];
#pragma unroll
  for (int j = 0; j < NLD; ++j) {
    int s = tid + 256 * j;
    const float* src = (s < CIB * PLN) ? heB : htB;
    float v = src[po[j]];
    stg[j] = ((okm >> j) & 1) ? v : 0.f;
  }

  float acc[9][4];
#pragma unroll
  for (int c = 0; c < 9; ++c) {
    float bv = (sp == 0) ? ((c < 8) ? b3e[c] : b3t[0]) : 0.f;
#pragma unroll
    for (int dy = 0; dy < 4; ++dy) acc[c][dy] = bv;
  }

  for (int cb = 0; cb < 8; cb += CIB) {
    __syncthreads();
#pragma unroll
    for (int j = 0; j < NLD; ++j) {
      int s = tid + 256 * j;
      if (s < NST) ((float*)sT)[s] = stg[j];
    }
    __syncthreads();
    if (cb + CIB < 8) {
      const size_t off = (size_t)(cb + CIB) * HW;
#pragma unroll
      for (int j = 0; j < NLD; ++j) {
        int s = tid + 256 * j;
        const float* src = (s < CIB * PLN) ? (heB + off) : (htB + off);
        float v = src[po[j]];
        stg[j] = ((okm >> j) & 1) ? v : 0.f;
      }
    }
#pragma unroll
    for (int ci = 0; ci < CIB; ++ci) {
      const int cin = cin0 + cb + ci;
      float ive[6][3], ivt[6][3];
#pragma unroll
      for (int r = 0; r < 6; ++r)
#pragma unroll
        for (int s2 = 0; s2 < 3; ++s2) {
          ive[r][s2] = sT[0][ci][(4 * ty + r) * TC + tx + s2];
          ivt[r][s2] = sT[1][ci][(4 * ty + r) * TC + tx + s2];
        }
#pragma unroll
      for (int c = 0; c < 9; ++c) {
        // wave-uniform global weight reads -> scalar loads
        const float* wp = (c < 8) ? &w3e[((size_t)c * 64 + cin) * 9]
                                  : &w3t[(size_t)cin * 9];
        const float (*iv)[3] = (c < 8) ? ive : ivt;
#pragma unroll
        for (int dy = 0; dy < 4; ++dy) {
          acc[c][dy] += iv[dy + 0][0] * wp[0] + iv[dy + 0][1] * wp[1] +
                        iv[dy + 0][2] * wp[2] + iv[dy + 1][0] * wp[3] +
                        iv[dy + 1][1] * wp[4] + iv[dy + 1][2] * wp[5] +
                        iv[dy + 2][0] * wp[6] + iv[dy + 2][1] * wp[7] +
                        iv[dy + 2][2] * wp[8];
        }
      }
    }
  }

  float* pB = part + (size_t)sp * RTOT + (size_t)b * 9 * HW;
#pragma unroll
  for (int dy = 0; dy < 4; ++dy) {
    const int h = th0 + 4 * ty + dy, w = tw0 + tx;
#pragma unroll
    for (int c = 0; c < 9; ++c)
      pB[(size_t)c * HW + h * W_ + w] = acc[c][dy];
  }
}

// ---------------------------------------------------------------------------
// reduce the 8 conv3 partials into xe (c<8) and ltm (c==8).
// ---------------------------------------------------------------------------
__global__ __launch_bounds__(256) void reduce9_k(const float* __restrict__ part,
                                                 float* __restrict__ xe,
                                                 float* __restrict__ ltm) {
  int i = blockIdx.x * 256 + threadIdx.x;
  if (i >= RTOT) return;
  float s = 0.f;
#pragma unroll
  for (int sp = 0; sp < SPL; ++sp) s += part[(size_t)sp * RTOT + i];
  int p = i % HW;
  int c = (i / HW) % 9;
  int b = i / (9 * HW);
  if (c < 8)
    xe[((size_t)(b * 8 + c)) * HW + p] = s;
  else
    ltm[(size_t)b * HW + p] = s;
}

// ---------------------------------------------------------------------------
// prep: per (b,n) block (256 thr): write pe row (from xe), yp row (from x),
// reduce sq = ||pe||^2 and lt = mean of 10x10 ltm patch. (unchanged)
// ---------------------------------------------------------------------------
__global__ __launch_bounds__(256) void prep_k(const float* __restrict__ xe,
                                              const float* __restrict__ x,
                                              const float* __restrict__ ltm,
                                              float* __restrict__ pe,
                                              float* __restrict__ yp,
                                              float* __restrict__ lt,
                                              float* __restrict__ sq) {
  const int n = blockIdx.x, b = blockIdx.y;
  const int tid = threadIdx.x;
  const int wv = tid >> 6, lane = tid & 63;
  const int q1 = n / N2, q2 = n % N2;
  const int r0 = q1 * 5, c0 = q2 * 5;

  float s = 0.f;
  float* peR = pe + ((size_t)b * N_ + n) * D_;
  float* ypR = yp + ((size_t)b * N_ + n) * D_;
#pragma unroll
  for (int j = 0; j < 4; ++j) {
    int d = tid + 256 * j;
    if (d < D_) {
      int c = d / 100;
      int rr = (d / 10) % 10;
      int cc = d % 10;
      size_t si = ((size_t)(b * 8 + c) * H_ + r0 + rr) * W_ + c0 + cc;
      float ve = xe[si];
      float vx = x[si];
      peR[d] = ve;
      ypR[d] = vx;
      s += ve * ve;
    }
  }
  float t = 0.f;
  if (tid < 100) t = ltm[(size_t)b * HW + (r0 + tid / 10) * W_ + c0 + tid % 10];

#pragma unroll
  for (int off = 32; off > 0; off >>= 1) {
    s += __shfl_xor(s, off);
    t += __shfl_xor(t, off);
  }
  __shared__ float rs[4], rt[4];
  if (lane == 0) { rs[wv] = s; rt[wv] = t; }
  __syncthreads();
  if (tid == 0) {
    sq[b * N_ + n] = rs[0] + rs[1] + rs[2] + rs[3];
    lt[b * N_ + n] = (rt[0] + rt[1] + rt[2] + rt[3]) * 0.01f;
  }
}

// ---------------------------------------------------------------------------
// attn stage 1 (unchanged).
// ---------------------------------------------------------------------------
__global__ __launch_bounds__(256) void attn_w_k(const float* __restrict__ pe,
                                                const float* __restrict__ lt,
                                                const float* __restrict__ sq,
                                                float* __restrict__ wk) {
  const int wv = threadIdx.x >> 6, lane = threadIdx.x & 63;
  const int n = blockIdx.x * 4 + wv;
  if (n >= N_) return;
  const int b = blockIdx.y;
  const int q1 = n / N2, q2 = n % N2;

  const float* peB = pe + (size_t)b * N_ * D_;
  const float* qrow = peB + (size_t)n * D_;
  float q[13];
#pragma unroll
  for (int t = 0; t < 13; ++t) {
    int s = t * 64 + lane;
    q[t] = (s < D_) ? qrow[s] : 0.f;
  }

  const float sqn = sq[b * N_ + n];
  const float itemp = expf(-lt[b * N_ + n]);
  float gm = -INFINITY;

  for (int o1 = 0; o1 < 7; ++o1) {
    int c1 = clampi(q1 + o1 - 3, 0, N1 - 1);
    const float* rowb = peB + (size_t)(c1 * N2) * D_;
#pragma unroll
    for (int o2 = 0; o2 < 7; ++o2) {
      int c2 = clampi(q2 + o2 - 3, 0, N2 - 1);
      int cn = c1 * N2 + c2;
      const float* crow = rowb + (size_t)c2 * D_;
      float a = 0.f;
#pragma unroll
      for (int t = 0; t < 13; ++t) {
        float v;
        if (t < 12) v = crow[t * 64 + lane];
        else v = (lane < 32) ? crow[768 + lane] : 0.f;
        a += q[t] * v;
      }
#pragma unroll
      for (int off = 32; off > 0; off >>= 1) a += __shfl_xor(a, off);
      float Dv = -(sqn + sq[b * N_ + cn] - 2.f * a);
      float lg = (cn == n) ? -1e9f : Dv * itemp;
      const int m = o1 * 7 + o2;
      gm = (lane == m) ? lg : gm;
    }
  }

  float cur = (lane < M_) ? gm : -INFINITY;
  float* wrow = wk + (size_t)(b * N_ + n) * (M_ * K_);
#pragma unroll
  for (int k = 0; k < K_; ++k) {
    float mx = cur;
#pragma unroll
    for (int off = 32; off > 0; off >>= 1) mx = fmaxf(mx, __shfl_xor(mx, off));
    float e = (lane < M_) ? expf(cur - mx) : 0.f;
    float ssum = e;
#pragma unroll
    for (int off = 32; off > 0; off >>= 1) ssum += __shfl_xor(ssum, off);
    float w = e / ssum;
    if (lane < M_) wrow[lane * K_ + k] = w;
    cur += log1pf(-fminf(w, 1.f - 1e-6f));
  }
}

// ---------------------------------------------------------------------------
// attn stage 2 (unchanged).
// ---------------------------------------------------------------------------
__global__ __launch_bounds__(256) void attn_pv_k(const float* __restrict__ yp,
                                                 const float* __restrict__ wk,
                                                 float* __restrict__ nb) {
  const int wv = threadIdx.x >> 6, lane = threadIdx.x & 63;
  const int n = blockIdx.x;
  const int b = blockIdx.z;
  const int sl = blockIdx.y * 4 + wv;
  const int d = sl * 64 + lane;
  if (d >= D_) return;
  const int q1 = n / N2, q2 = n % N2;

  const float* ypB = yp + (size_t)b * N_ * D_;
  const float* wrow = wk + (size_t)(b * N_ + n) * (M_ * K_);

  float acc[K_];
#pragma unroll
  for (int k = 0; k < K_; ++k) acc[k] = 0.f;

#pragma unroll
  for (int o1 = 0; o1 < 7; ++o1) {
    int c1 = clampi(q1 + o1 - 3, 0, N1 - 1);
#pragma unroll
    for (int o2 = 0; o2 < 7; ++o2) {
      int c2 = clampi(q2 + o2 - 3, 0, N2 - 1);
      int cn = c1 * N2 + c2;
      float y = ypB[(size_t)cn * D_ + d];
      const int m = o1 * 7 + o2;
#pragma unroll
      for (int k = 0; k < K_; ++k) acc[k] += wrow[m * K_ + k] * y;
    }
  }
#pragma unroll
  for (int k = 0; k < K_; ++k)
    nb[(((size_t)k * B_ + b) * N_ + n) * D_ + d] = acc[k];
}

// ---------------------------------------------------------------------------
// Fused output: channels 0..7 copy x; channels 8..63 fold-gather from nb.
// ---------------------------------------------------------------------------
__global__ __launch_bounds__(256) void foldcopy_k(const float* __restrict__ x,
                                                  const float* __restrict__ nb,
                                                  float* __restrict__ out) {
  int i = blockIdx.x * 256 + threadIdx.x;
  constexpr int CT = CIN * (K_ + 1);  // 64
  constexpr int TOT = B_ * CT * HW;
  if (i >= TOT) return;
  int w = i % W_;
  int h = (i / W_) % H_;
  int c64 = (i / HW) % CT;
  int b = i / (HW * CT);
  if (c64 < CIN) {
    out[i] = x[((size_t)b * CIN + c64) * HW + h * W_ + w];
    return;
  }
  int k = (c64 - CIN) >> 3, c = (c64 - CIN) & 7;
  int q1lo = max(0, (h - 5) / 5), q1hi = min(N1 - 1, h / 5);
  int q2lo = max(0, (w - 5) / 5), q2hi = min(N2 - 1, w / 5);
  float val = 0.f;
  int cnt = 0;
  for (int q1 = q1lo; q1 <= q1hi; ++q1)
    for (int q2 = q2lo; q2 <= q2hi; ++q2) {
      int i0 = h - 5 * q1, j0 = w - 5 * q2;
      int nn = q1 * N2 + q2;
      val += nb[(((size_t)k * B_ + b) * N_ + nn) * D_ + c * 100 + i0 * 10 + j0];
      ++cnt;
    }
  out[i] = (cnt > 0) ? val / (float)cnt : 0.f;
}

extern "C" void kernel_launch(void* const* d_in, const int* in_sizes, int n_in,
                              void* d_out, int out_size, void* d_ws,
                              size_t ws_size, hipStream_t stream) {
  const float* x   = (const float*)d_in[0];
  const float* w1e = (const float*)d_in[1];
  const float* b1e = (const float*)d_in[2];
  const float* w2e = (const float*)d_in[3];
  const float* b2e = (const float*)d_in[4];
  const float* w3e = (const float*)d_in[5];
  const float* b3e = (const float*)d_in[6];
  const float* w1t = (const float*)d_in[7];
  const float* b1t = (const float*)d_in[8];
  const float* w2t = (const float*)d_in[9];
  const float* b2t = (const float*)d_in[10];
  const float* w3t = (const float*)d_in[11];
  const float* b3t = (const float*)d_in[12];

  float* ws  = (float*)d_ws;
  float* out = (float*)d_out;

  float* h1e = ws + OFF_H1E;   // channels-last
  float* h1t = ws + OFF_H1T;   // channels-last
  float* h2e = ws + OFF_H2E;   // NCHW
  float* h2t = ws + OFF_H2T;   // NCHW
  float* wkb = ws + OFF_WK;
  float* nb  = ws + OFF_NB;
  float* xe  = ws + OFF_XE;
  float* ltm = ws + OFF_LTM;
  float* pe  = ws + OFF_PE;
  float* yp  = ws + OFF_YP;
  float* lt  = ws + OFF_LT;
  float* sqv = ws + OFF_SQ;
  unsigned short* whi = (unsigned short*)(ws + OFF_XE);  // consumed before xe written
  unsigned short* wlo = whi + WPREP_N;
  float* part = ws + OFF_H1E;  // conv3 partials over dead h1 region

  // conv2 weight prep
  wprep_k<<<(WPREP_N + 255) / 256, 256, 0, stream>>>(w2e, w2t, whi, wlo);
  // conv1 (8 -> 64, relu), e+t in one dispatch, channels-last output
  conv1m_k<<<dim3(4, 49, 4), 256, 0, stream>>>(x, w1e, b1e, h1e, w1t, b1t, h1t);
  // conv2 (64 -> 64, relu) via MFMA, both branches + batches in one dispatch
  conv2_mfma_k<<<dim3(196, 1, 4), 256, 0, stream>>>(h1e, h1t, whi, wlo, b2e, b2t, h2e, h2t);
  // conv3 (64 -> 8 + 64 -> 1) merged, cin split 8 ways -> 784 blocks
  conv3s_k<<<dim3(49, B_, SPL), 256, 0, stream>>>(h2e, h2t, w3e, w3t, b3e, b3t, part);
  // sum partials into xe / ltm
  reduce9_k<<<(RTOT + 255) / 256, 256, 0, stream>>>(part, xe, ltm);
  // patches + norms + log-temp means fused
  prep_k<<<dim3(N_, B_), 256, 0, stream>>>(xe, x, ltm, pe, yp, lt, sqv);
  // attention stage 1: weights
  attn_w_k<<<dim3((N_ + 3) / 4, B_), 256, 0, stream>>>(pe, lt, sqv, wkb);
  // attention stage 2: weighted neighbor sums
  attn_pv_k<<<dim3(N_, 4, B_), 256, 0, stream>>>(yp, wkb, nb);
  // fused fold + x passthrough
  constexpr int FT = B_ * CIN * (K_ + 1) * HW;
  foldcopy_k<<<(FT + 255) / 256, 256, 0, stream>>>(x, nb, out);
}

// Round 5
// 365.494 us; speedup vs baseline: 1.3494x; 1.1315x over previous
//
#include <hip/hip_runtime.h>
#include <math.h>

namespace {
constexpr int B_ = 2, CIN = 8, H_ = 224, W_ = 224;
constexpr int K_ = 7;
constexpr int F_ = 64, E_ = 8;
constexpr int N1 = 43, N2 = 43, N_ = N1 * N2;   // 1849
constexpr int M_ = 49;                           // candidates per query
constexpr int D_ = 800;                          // patch dim (C*P*P)
constexpr int HW = H_ * W_;

// workspace layout (floats).
constexpr size_t FHW = (size_t)B_ * F_ * HW;     // 6,422,528
constexpr size_t OFF_H1E = 0;                    // channels-last [b][h][w][64]
constexpr size_t OFF_H1T = OFF_H1E + FHW;
constexpr size_t OFF_H2E = OFF_H1T + FHW;        // NCHW
constexpr size_t OFF_H2T = OFF_H2E + FHW;
constexpr size_t OFF_WK  = 0;                                  // B*N*343
constexpr size_t OFF_NB  = 1280000;                            // > Wk end
constexpr size_t OFF_XE  = OFF_H2T + FHW;
constexpr size_t OFF_LTM = OFF_XE + (size_t)B_ * E_ * HW;
constexpr size_t OFF_PE  = OFF_LTM + (size_t)B_ * HW;
constexpr size_t OFF_YP  = OFF_PE + (size_t)B_ * N_ * D_;
constexpr size_t OFF_LT  = OFF_YP + (size_t)B_ * N_ * D_;
constexpr size_t OFF_SQ  = OFF_LT + (size_t)B_ * N_;
// conv weights (prepped bf16 hi/lo) overlap the xe region (consumed before
// reduce9 writes xe): (2*294912 + 2*12288) shorts = 307,200 floats < 802,816.
constexpr int WPREP_N = 294912;   // conv2: 2br * 2kcb * 9idx * 4wv * 64lane * 8j
constexpr int WPREP1_N = 12288;   // conv1: 2br * 3ky * 4wv * 64lane * 8j
constexpr int WPREP_TOT = WPREP_N + WPREP1_N;

// conv3 split partials live in the dead h1e/h1t region (conv2 inputs,
// consumed before conv3 runs): 8 * B * 9 * HW = 7,225,344 < 12,845,056.
constexpr int SPL = 8;                            // cin splits for conv3
constexpr int RTOT = B_ * 9 * HW;                 // 903,168 per split

__device__ __forceinline__ int clampi(int v, int lo, int hi) {
  return min(max(v, lo), hi);
}

typedef __attribute__((ext_vector_type(8))) short short8;
typedef __attribute__((ext_vector_type(4))) float float4v;
} // namespace

// ---------------------------------------------------------------------------
// Weight prep: conv2 (t < WPREP_N) and conv1 (rest) bf16 hi/lo splits.
// conv1 A-fragment: co = wv*16+(lane&15); K = 8*(lane>>4)+j -> (kx=lane>>4,
// ci=j); kx==3 is K-padding (zero).
// ---------------------------------------------------------------------------
__global__ __launch_bounds__(256) void wprep_k(
    const float* __restrict__ w_e, const float* __restrict__ w_t,
    const float* __restrict__ w1e, const float* __restrict__ w1t,
    unsigned short* __restrict__ whi, unsigned short* __restrict__ wlo,
    unsigned short* __restrict__ whi1, unsigned short* __restrict__ wlo1) {
  int t = blockIdx.x * 256 + threadIdx.x;
  if (t >= WPREP_TOT) return;
  float v;
  unsigned short* dh;
  unsigned short* dl;
  int di;
  if (t < WPREP_N) {
    int j = t & 7;
    int lane = (t >> 3) & 63;
    int wv = (t >> 9) & 3;
    int t2 = t >> 11;
    int idx = t2 % 9;
    int t3 = t2 / 9;
    int kcb = t3 & 1;
    int br = t3 >> 1;
    const float* wgt = br ? w_t : w_e;
    int co = wv * 16 + (lane & 15);
    int ci = kcb * 32 + 8 * (lane >> 4) + j;
    v = wgt[((size_t)co * 64 + ci) * 9 + idx];
    dh = whi; dl = wlo; di = t;
  } else {
    int t1 = t - WPREP_N;
    int j = t1 & 7;
    int lane = (t1 >> 3) & 63;
    int wv = (t1 >> 9) & 3;
    int t2 = t1 >> 11;
    int ky = t2 % 3;
    int br = t2 / 3;
    const float* wgt = br ? w1t : w1e;
    int co = wv * 16 + (lane & 15);
    int kx = lane >> 4;
    int ci = j;
    v = (kx < 3) ? wgt[(((size_t)co * 8 + ci) * 3 + ky) * 3 + kx] : 0.f;
    dh = whi1; dl = wlo1; di = t1;
  }
  unsigned u = __float_as_uint(v);
  unsigned short hi = (unsigned short)(u >> 16);
  float rem = v - __uint_as_float(u & 0xffff0000u);
  unsigned short lo = (unsigned short)(__float_as_uint(rem) >> 16);
  dh[di] = hi;
  dl[di] = lo;
}

// ---------------------------------------------------------------------------
// conv1 (8->64, relu) via MFMA bf16 3-term hi/lo split (R12). 16x16 pixel
// tile, 4 waves = 64 couts, K = (kx,ci) packed into MFMA K=32 (q=3 zero-pad),
// ky via acc-row shift (conv2's trick). Single staging round (no kcb loop):
// x tile 18x19x8 as bf16 hi/lo in LDS (stride 20 shorts -> 2-way banks).
// Output channels-last [b][h][w][64] for conv2.
// ---------------------------------------------------------------------------
__global__ __launch_bounds__(256) void conv1_k(
    const float* __restrict__ x,
    const unsigned short* __restrict__ whi1, const unsigned short* __restrict__ wlo1,
    const float* __restrict__ b_e, float* __restrict__ o_e,
    const float* __restrict__ b_t, float* __restrict__ o_t) {
  const int tile = blockIdx.x;
  const int b = blockIdx.z & 1;
  const int br = blockIdx.z >> 1;
  const float* bias = br ? b_t : b_e;
  float* out = br ? o_t : o_e;

  const int th0 = (tile / 14) * 16, tw0 = (tile % 14) * 16;
  const int tid = threadIdx.x;
  const int wv = tid >> 6, lane = tid & 63;
  const int q = lane >> 4, n = lane & 15;

  __shared__ unsigned short sT[342 * 20];   // 18 rows x 19 cols x (8hi+8lo), 13680 B

  // ---- stage x tile (fp32 -> bf16 hi/lo), zero-padded halo + pad col 18 ----
  const float* xB = x + (size_t)b * CIN * HW;
#pragma unroll
  for (int it = 0; it < 2; ++it) {
    int s = tid + 256 * it;
    if (s < 342) {
      int lr = s / 19, lc = s - lr * 19;
      int gh = th0 + lr - 1, gw = tw0 + lc - 1;
      short8 h8, l8;
#pragma unroll
      for (int ci = 0; ci < 8; ++ci) { h8[ci] = 0; l8[ci] = 0; }
      if (lc < 18 && gh >= 0 && gh < H_ && gw >= 0 && gw < W_) {
        const float* xp = xB + (size_t)gh * W_ + gw;
#pragma unroll
        for (int ci = 0; ci < 8; ++ci) {
          float v = xp[(size_t)ci * HW];
          unsigned u = __float_as_uint(v);
          float rem = v - __uint_as_float(u & 0xffff0000u);
          h8[ci] = (short)(u >> 16);
          l8[ci] = (short)(__float_as_uint(rem) >> 16);
        }
      }
      *(short8*)&sT[s * 20] = h8;
      *(short8*)&sT[s * 20 + 8] = l8;
    }
  }

  // ---- A fragments (weights), 3 ky ----
  const short8* wh8 = (const short8*)whi1;
  const short8* wl8 = (const short8*)wlo1;
  short8 Ah[3], Al[3];
#pragma unroll
  for (int ky = 0; ky < 3; ++ky) {
    int ab = ((br * 3 + ky) * 4 + wv) * 64 + lane;
    Ah[ky] = wh8[ab];
    Al[ky] = wl8[ab];
  }

  float4v acc[16];
#pragma unroll
  for (int pr = 0; pr < 16; ++pr) acc[pr] = (float4v)0.f;

  __syncthreads();

  // ---- main loop: 18 padded rows, ky folded via acc-row shift ----
#pragma unroll
  for (int r = 0; r < 18; ++r) {
    const unsigned short* p = &sT[(r * 19 + n + q) * 20];
    short8 Bh = *(const short8*)p;
    short8 Bl = *(const short8*)(p + 8);
#pragma unroll
    for (int ky = 0; ky < 3; ++ky) {
      const int pr = r - ky;
      if (pr >= 0 && pr < 16) {
        acc[pr] = __builtin_amdgcn_mfma_f32_16x16x32_bf16(Ah[ky], Bh, acc[pr], 0, 0, 0);
        acc[pr] = __builtin_amdgcn_mfma_f32_16x16x32_bf16(Al[ky], Bh, acc[pr], 0, 0, 0);
        acc[pr] = __builtin_amdgcn_mfma_f32_16x16x32_bf16(Ah[ky], Bl, acc[pr], 0, 0, 0);
      }
    }
  }

  // ---- epilogue: bias + relu, channels-last float4 stores ----
  float4v bv = *(const float4v*)&bias[wv * 16 + 4 * q];
#pragma unroll
  for (int pr = 0; pr < 16; ++pr) {
    float4v v;
#pragma unroll
    for (int r = 0; r < 4; ++r) v[r] = fmaxf(acc[pr][r] + bv[r], 0.f);
    *(float4v*)&out[(((size_t)b * H_ + th0 + pr) * W_ + tw0 + n) * 64 + wv * 16 + 4 * q] = v;
  }
}

// ---------------------------------------------------------------------------
// conv2 (64->64, relu) via MFMA bf16 3-term hi/lo split (unchanged).
// ---------------------------------------------------------------------------
__global__ __launch_bounds__(256) void conv2_mfma_k(
    const float* __restrict__ in_e, const float* __restrict__ in_t,
    const unsigned short* __restrict__ whi, const unsigned short* __restrict__ wlo,
    const float* __restrict__ b_e, const float* __restrict__ b_t,
    float* __restrict__ out_e, float* __restrict__ out_t) {
  const int tile = blockIdx.x;
  const int b = blockIdx.z & 1;
  const int br = blockIdx.z >> 1;
  const float* in = br ? in_t : in_e;
  const float* bias = br ? b_t : b_e;
  float* out = br ? out_t : out_e;

  const int th0 = (tile / 14) * 16, tw0 = (tile % 14) * 16;
  const int tid = threadIdx.x;
  const int wv = tid >> 6, lane = tid & 63;
  const int q = lane >> 4, n = lane & 15;

  __shared__ unsigned short sT[18 * 18 * 72];
  unsigned* sT32 = (unsigned*)sT;

  float4v acc[16];
#pragma unroll
  for (int pr = 0; pr < 16; ++pr) acc[pr] = (float4v)0.f;

  const float* inB = in + (size_t)b * HW * 64;
  const short8* whi8 = (const short8*)whi;
  const short8* wlo8 = (const short8*)wlo;

  for (int kcb = 0; kcb < 2; ++kcb) {
    __syncthreads();
    for (int jj = 0; jj < 21; ++jj) {
      int s = tid + 256 * jj;
      if (s < 5184) {
        int sp = s >> 4, cp = s & 15;
        int lr = sp / 18, lc = sp - lr * 18;
        int gh = th0 + lr - 1, gw = tw0 + lc - 1;
        float vx = 0.f, vy = 0.f;
        if (gh >= 0 && gh < H_ && gw >= 0 && gw < W_) {
          const float2 vv =
              *(const float2*)&inB[((size_t)gh * W_ + gw) * 64 + kcb * 32 + 2 * cp];
          vx = vv.x; vy = vv.y;
        }
        unsigned u0 = __float_as_uint(vx), u1 = __float_as_uint(vy);
        float r0 = vx - __uint_as_float(u0 & 0xffff0000u);
        float r1 = vy - __uint_as_float(u1 & 0xffff0000u);
        unsigned l0 = __float_as_uint(r0) >> 16, l1 = __float_as_uint(r1) >> 16;
        sT32[sp * 36 + cp] = (u0 >> 16) | ((u1 >> 16) << 16);
        sT32[sp * 36 + 16 + cp] = l0 | (l1 << 16);
      }
    }
    __syncthreads();

    short8 Ah[9], Al[9];
    const int abase = (((br * 2 + kcb) * 9) * 4 + wv) * 64 + lane;
#pragma unroll
    for (int idx = 0; idx < 9; ++idx) {
      Ah[idx] = whi8[abase + idx * 256];
      Al[idx] = wlo8[abase + idx * 256];
    }

#pragma unroll
    for (int r = 0; r < 18; ++r) {
      short8 Bh[3], Bl[3];
#pragma unroll
      for (int kx = 0; kx < 3; ++kx) {
        const unsigned short* p = &sT[(r * 18 + n + kx) * 72 + 8 * q];
        Bh[kx] = *(const short8*)p;
        Bl[kx] = *(const short8*)(p + 32);
      }
#pragma unroll
      for (int ky = 0; ky < 3; ++ky) {
        const int pr = r - ky;
        if (pr >= 0 && pr < 16) {
#pragma unroll
          for (int kx = 0; kx < 3; ++kx) {
            const int idx = ky * 3 + kx;
            acc[pr] = __builtin_amdgcn_mfma_f32_16x16x32_bf16(Ah[idx], Bh[kx], acc[pr], 0, 0, 0);
            acc[pr] = __builtin_amdgcn_mfma_f32_16x16x32_bf16(Al[idx], Bh[kx], acc[pr], 0, 0, 0);
            acc[pr] = __builtin_amdgcn_mfma_f32_16x16x32_bf16(Ah[idx], Bl[kx], acc[pr], 0, 0, 0);
          }
        }
      }
    }
  }

  float4v bv = *(const float4v*)&bias[wv * 16 + 4 * q];
#pragma unroll
  for (int pr = 0; pr < 16; ++pr) {
#pragma unroll
    for (int r = 0; r < 4; ++r) {
      int co = wv * 16 + 4 * q + r;
      float v = fmaxf(acc[pr][r] + bv[r], 0.f);
      out[((size_t)b * 64 + co) * HW + (th0 + pr) * W_ + tw0 + n] = v;
    }
  }
}

// ---------------------------------------------------------------------------
// conv3 e+t merged, cin split 8 ways (grid z), 32x32 tile, 4 rows/thread,
// CIB=2, weights via wave-uniform global reads. (unchanged)
// ---------------------------------------------------------------------------
__global__ __launch_bounds__(256) void conv3s_k(
    const float* __restrict__ h2e, const float* __restrict__ h2t,
    const float* __restrict__ w3e, const float* __restrict__ w3t,
    const float* __restrict__ b3e, const float* __restrict__ b3t,
    float* __restrict__ part) {
  constexpr int CIB = 2;
  constexpr int TR = 34, TC = 34;             // padded tile 34 x 34
  constexpr int PLN = TR * TC;                // 1156
  constexpr int NST = 2 * CIB * PLN;          // 4624 (both branches)
  constexpr int NLD = (NST + 255) / 256;      // 19

  const int tile = blockIdx.x;                // 0..48 (7 x 7)
  const int b = blockIdx.y;
  const int sp = blockIdx.z;                  // cin split 0..7
  const int cin0 = sp * 8;
  const int th0 = (tile / 7) * 32, tw0 = (tile % 7) * 32;
  const int tid = threadIdx.x;
  const int tx = tid & 31, ty = tid >> 5;     // 4 rows per thread

  __shared__ float sT[2][CIB][PLN];           // 18496 B

  int po[NLD];
  unsigned okm = 0;
#pragma unroll
  for (int j = 0; j < NLD; ++j) {
    int s = tid + 256 * j;
    int rem2 = s % (CIB * PLN);
    int pl = rem2 / PLN, rem = rem2 % PLN;
    int lr = rem / TC, lc = rem - lr * TC;
    int gh = th0 + lr - 1, gw = tw0 + lc - 1;
    bool ok = (s < NST) && gh >= 0 && gh < H_ && gw >= 0 && gw < W_;
    po[j] = ok ? (pl * HW + gh * W_ + gw) : 0;
    if (ok) okm |= (1u << j);
  }

  const float* heB = h2e + ((size_t)b * 64 + cin0) * HW;
  const float* htB = h2t + ((size_t)b * 64 + cin0) * HW;

  float stg[NLD];
#pragma unroll
  for (int j = 0; j < NLD; ++j) {
    int s = tid + 256 * j;
    const float* src = (s < CIB * PLN) ? heB : htB;
    float v = src[po[j]];
    stg[j] = ((okm >> j) & 1) ? v : 0.f;
  }

  float acc[9][4];
#pragma unroll
  for (int c = 0; c < 9; ++c) {
    float bv = (sp == 0) ? ((c < 8) ? b3e[c] : b3t[0]) : 0.f;
#pragma unroll
    for (int dy = 0; dy < 4; ++dy) acc[c][dy] = bv;
  }

  for (int cb = 0; cb < 8; cb += CIB) {
    __syncthreads();
#pragma unroll
    for (int j = 0; j < NLD; ++j) {
      int s = tid + 256 * j;
      if (s < NST) ((float*)sT)[s] = stg[j];
    }
    __syncthreads();
    if (cb + CIB < 8) {
      const size_t off = (size_t)(cb + CIB) * HW;
#pragma unroll
      for (int j = 0; j < NLD; ++j) {
        int s = tid + 256 * j;
        const float* src = (s < CIB * PLN) ? (heB + off) : (htB + off);
        float v = src[po[j]];
        stg[j] = ((okm >> j) & 1) ? v : 0.f;
      }
    }
#pragma unroll
    for (int ci = 0; ci < CIB; ++ci) {
      const int cin = cin0 + cb + ci;
      float ive[6][3], ivt[6][3];
#pragma unroll
      for (int r = 0; r < 6; ++r)
#pragma unroll
        for (int s2 = 0; s2 < 3; ++s2) {
          ive[r][s2] = sT[0][ci][(4 * ty + r) * TC + tx + s2];
          ivt[r][s2] = sT[1][ci][(4 * ty + r) * TC + tx + s2];
        }
#pragma unroll
      for (int c = 0; c < 9; ++c) {
        // wave-uniform global weight reads -> scalar loads
        const float* wp = (c < 8) ? &w3e[((size_t)c * 64 + cin) * 9]
                                  : &w3t[(size_t)cin * 9];
        const float (*iv)[3] = (c < 8) ? ive : ivt;
#pragma unroll
        for (int dy = 0; dy < 4; ++dy) {
          acc[c][dy] += iv[dy + 0][0] * wp[0] + iv[dy + 0][1] * wp[1] +
                        iv[dy + 0][2] * wp[2] + iv[dy + 1][0] * wp[3] +
                        iv[dy + 1][1] * wp[4] + iv[dy + 1][2] * wp[5] +
                        iv[dy + 2][0] * wp[6] + iv[dy + 2][1] * wp[7] +
                        iv[dy + 2][2] * wp[8];
        }
      }
    }
  }

  float* pB = part + (size_t)sp * RTOT + (size_t)b * 9 * HW;
#pragma unroll
  for (int dy = 0; dy < 4; ++dy) {
    const int h = th0 + 4 * ty + dy, w = tw0 + tx;
#pragma unroll
    for (int c = 0; c < 9; ++c)
      pB[(size_t)c * HW + h * W_ + w] = acc[c][dy];
  }
}

// ---------------------------------------------------------------------------
// reduce the 8 conv3 partials into xe (c<8) and ltm (c==8).
// ---------------------------------------------------------------------------
__global__ __launch_bounds__(256) void reduce9_k(const float* __restrict__ part,
                                                 float* __restrict__ xe,
                                                 float* __restrict__ ltm) {
  int i = blockIdx.x * 256 + threadIdx.x;
  if (i >= RTOT) return;
  float s = 0.f;
#pragma unroll
  for (int sp = 0; sp < SPL; ++sp) s += part[(size_t)sp * RTOT + i];
  int p = i % HW;
  int c = (i / HW) % 9;
  int b = i / (9 * HW);
  if (c < 8)
    xe[((size_t)(b * 8 + c)) * HW + p] = s;
  else
    ltm[(size_t)b * HW + p] = s;
}

// ---------------------------------------------------------------------------
// prep: per (b,n) block (256 thr): write pe row (from xe), yp row (from x),
// reduce sq = ||pe||^2 and lt = mean of 10x10 ltm patch. (unchanged)
// ---------------------------------------------------------------------------
__global__ __launch_bounds__(256) void prep_k(const float* __restrict__ xe,
                                              const float* __restrict__ x,
                                              const float* __restrict__ ltm,
                                              float* __restrict__ pe,
                                              float* __restrict__ yp,
                                              float* __restrict__ lt,
                                              float* __restrict__ sq) {
  const int n = blockIdx.x, b = blockIdx.y;
  const int tid = threadIdx.x;
  const int wv = tid >> 6, lane = tid & 63;
  const int q1 = n / N2, q2 = n % N2;
  const int r0 = q1 * 5, c0 = q2 * 5;

  float s = 0.f;
  float* peR = pe + ((size_t)b * N_ + n) * D_;
  float* ypR = yp + ((size_t)b * N_ + n) * D_;
#pragma unroll
  for (int j = 0; j < 4; ++j) {
    int d = tid + 256 * j;
    if (d < D_) {
      int c = d / 100;
      int rr = (d / 10) % 10;
      int cc = d % 10;
      size_t si = ((size_t)(b * 8 + c) * H_ + r0 + rr) * W_ + c0 + cc;
      float ve = xe[si];
      float vx = x[si];
      peR[d] = ve;
      ypR[d] = vx;
      s += ve * ve;
    }
  }
  float t = 0.f;
  if (tid < 100) t = ltm[(size_t)b * HW + (r0 + tid / 10) * W_ + c0 + tid % 10];

#pragma unroll
  for (int off = 32; off > 0; off >>= 1) {
    s += __shfl_xor(s, off);
    t += __shfl_xor(t, off);
  }
  __shared__ float rs[4], rt[4];
  if (lane == 0) { rs[wv] = s; rt[wv] = t; }
  __syncthreads();
  if (tid == 0) {
    sq[b * N_ + n] = rs[0] + rs[1] + rs[2] + rs[3];
    lt[b * N_ + n] = (rt[0] + rt[1] + rt[2] + rt[3]) * 0.01f;
  }
}

// ---------------------------------------------------------------------------
// attn stage 1 (unchanged).
// ---------------------------------------------------------------------------
__global__ __launch_bounds__(256) void attn_w_k(const float* __restrict__ pe,
                                                const float* __restrict__ lt,
                                                const float* __restrict__ sq,
                                                float* __restrict__ wk) {
  const int wv = threadIdx.x >> 6, lane = threadIdx.x & 63;
  const int n = blockIdx.x * 4 + wv;
  if (n >= N_) return;
  const int b = blockIdx.y;
  const int q1 = n / N2, q2 = n % N2;

  const float* peB = pe + (size_t)b * N_ * D_;
  const float* qrow = peB + (size_t)n * D_;
  float q[13];
#pragma unroll
  for (int t = 0; t < 13; ++t) {
    int s = t * 64 + lane;
    q[t] = (s < D_) ? qrow[s] : 0.f;
  }

  const float sqn = sq[b * N_ + n];
  const float itemp = expf(-lt[b * N_ + n]);
  float gm = -INFINITY;

  for (int o1 = 0; o1 < 7; ++o1) {
    int c1 = clampi(q1 + o1 - 3, 0, N1 - 1);
    const float* rowb = peB + (size_t)(c1 * N2) * D_;
#pragma unroll
    for (int o2 = 0; o2 < 7; ++o2) {
      int c2 = clampi(q2 + o2 - 3, 0, N2 - 1);
      int cn = c1 * N2 + c2;
      const float* crow = rowb + (size_t)c2 * D_;
      float a = 0.f;
#pragma unroll
      for (int t = 0; t < 13; ++t) {
        float v;
        if (t < 12) v = crow[t * 64 + lane];
        else v = (lane < 32) ? crow[768 + lane] : 0.f;
        a += q[t] * v;
      }
#pragma unroll
      for (int off = 32; off > 0; off >>= 1) a += __shfl_xor(a, off);
      float Dv = -(sqn + sq[b * N_ + cn] - 2.f * a);
      float lg = (cn == n) ? -1e9f : Dv * itemp;
      const int m = o1 * 7 + o2;
      gm = (lane == m) ? lg : gm;
    }
  }

  float cur = (lane < M_) ? gm : -INFINITY;
  float* wrow = wk + (size_t)(b * N_ + n) * (M_ * K_);
#pragma unroll
  for (int k = 0; k < K_; ++k) {
    float mx = cur;
#pragma unroll
    for (int off = 32; off > 0; off >>= 1) mx = fmaxf(mx, __shfl_xor(mx, off));
    float e = (lane < M_) ? expf(cur - mx) : 0.f;
    float ssum = e;
#pragma unroll
    for (int off = 32; off > 0; off >>= 1) ssum += __shfl_xor(ssum, off);
    float w = e / ssum;
    if (lane < M_) wrow[lane * K_ + k] = w;
    cur += log1pf(-fminf(w, 1.f - 1e-6f));
  }
}

// ---------------------------------------------------------------------------
// attn stage 2 (unchanged).
// ---------------------------------------------------------------------------
__global__ __launch_bounds__(256) void attn_pv_k(const float* __restrict__ yp,
                                                 const float* __restrict__ wk,
                                                 float* __restrict__ nb) {
  const int wv = threadIdx.x >> 6, lane = threadIdx.x & 63;
  const int n = blockIdx.x;
  const int b = blockIdx.z;
  const int sl = blockIdx.y * 4 + wv;
  const int d = sl * 64 + lane;
  if (d >= D_) return;
  const int q1 = n / N2, q2 = n % N2;

  const float* ypB = yp + (size_t)b * N_ * D_;
  const float* wrow = wk + (size_t)(b * N_ + n) * (M_ * K_);

  float acc[K_];
#pragma unroll
  for (int k = 0; k < K_; ++k) acc[k] = 0.f;

#pragma unroll
  for (int o1 = 0; o1 < 7; ++o1) {
    int c1 = clampi(q1 + o1 - 3, 0, N1 - 1);
#pragma unroll
    for (int o2 = 0; o2 < 7; ++o2) {
      int c2 = clampi(q2 + o2 - 3, 0, N2 - 1);
      int cn = c1 * N2 + c2;
      float y = ypB[(size_t)cn * D_ + d];
      const int m = o1 * 7 + o2;
#pragma unroll
      for (int k = 0; k < K_; ++k) acc[k] += wrow[m * K_ + k] * y;
    }
  }
#pragma unroll
  for (int k = 0; k < K_; ++k)
    nb[(((size_t)k * B_ + b) * N_ + n) * D_ + d] = acc[k];
}

// ---------------------------------------------------------------------------
// Fused output: channels 0..7 copy x; channels 8..63 fold-gather from nb.
// ---------------------------------------------------------------------------
__global__ __launch_bounds__(256) void foldcopy_k(const float* __restrict__ x,
                                                  const float* __restrict__ nb,
                                                  float* __restrict__ out) {
  int i = blockIdx.x * 256 + threadIdx.x;
  constexpr int CT = CIN * (K_ + 1);  // 64
  constexpr int TOT = B_ * CT * HW;
  if (i >= TOT) return;
  int w = i % W_;
  int h = (i / W_) % H_;
  int c64 = (i / HW) % CT;
  int b = i / (HW * CT);
  if (c64 < CIN) {
    out[i] = x[((size_t)b * CIN + c64) * HW + h * W_ + w];
    return;
  }
  int k = (c64 - CIN) >> 3, c = (c64 - CIN) & 7;
  int q1lo = max(0, (h - 5) / 5), q1hi = min(N1 - 1, h / 5);
  int q2lo = max(0, (w - 5) / 5), q2hi = min(N2 - 1, w / 5);
  float val = 0.f;
  int cnt = 0;
  for (int q1 = q1lo; q1 <= q1hi; ++q1)
    for (int q2 = q2lo; q2 <= q2hi; ++q2) {
      int i0 = h - 5 * q1, j0 = w - 5 * q2;
      int nn = q1 * N2 + q2;
      val += nb[(((size_t)k * B_ + b) * N_ + nn) * D_ + c * 100 + i0 * 10 + j0];
      ++cnt;
    }
  out[i] = (cnt > 0) ? val / (float)cnt : 0.f;
}

extern "C" void kernel_launch(void* const* d_in, const int* in_sizes, int n_in,
                              void* d_out, int out_size, void* d_ws,
                              size_t ws_size, hipStream_t stream) {
  const float* x   = (const float*)d_in[0];
  const float* w1e = (const float*)d_in[1];
  const float* b1e = (const float*)d_in[2];
  const float* w2e = (const float*)d_in[3];
  const float* b2e = (const float*)d_in[4];
  const float* w3e = (const float*)d_in[5];
  const float* b3e = (const float*)d_in[6];
  const float* w1t = (const float*)d_in[7];
  const float* b1t = (const float*)d_in[8];
  const float* w2t = (const float*)d_in[9];
  const float* b2t = (const float*)d_in[10];
  const float* w3t = (const float*)d_in[11];
  const float* b3t = (const float*)d_in[12];

  float* ws  = (float*)d_ws;
  float* out = (float*)d_out;

  float* h1e = ws + OFF_H1E;   // channels-last
  float* h1t = ws + OFF_H1T;   // channels-last
  float* h2e = ws + OFF_H2E;   // NCHW
  float* h2t = ws + OFF_H2T;   // NCHW
  float* wkb = ws + OFF_WK;
  float* nb  = ws + OFF_NB;
  float* xe  = ws + OFF_XE;
  float* ltm = ws + OFF_LTM;
  float* pe  = ws + OFF_PE;
  float* yp  = ws + OFF_YP;
  float* lt  = ws + OFF_LT;
  float* sqv = ws + OFF_SQ;
  unsigned short* whi  = (unsigned short*)(ws + OFF_XE);  // consumed before xe written
  unsigned short* wlo  = whi + WPREP_N;
  unsigned short* whi1 = wlo + WPREP_N;
  unsigned short* wlo1 = whi1 + WPREP1_N;
  float* part = ws + OFF_H1E;  // conv3 partials over dead h1 region

  // weight prep (conv1 + conv2)
  wprep_k<<<(WPREP_TOT + 255) / 256, 256, 0, stream>>>(w2e, w2t, w1e, w1t,
                                                       whi, wlo, whi1, wlo1);
  // conv1 (8 -> 64, relu) via MFMA, channels-last output
  conv1_k<<<dim3(196, 1, 4), 256, 0, stream>>>(x, whi1, wlo1, b1e, h1e, b1t, h1t);
  // conv2 (64 -> 64, relu) via MFMA, both branches + batches in one dispatch
  conv2_mfma_k<<<dim3(196, 1, 4), 256, 0, stream>>>(h1e, h1t, whi, wlo, b2e, b2t, h2e, h2t);
  // conv3 (64 -> 8 + 64 -> 1) merged, cin split 8 ways -> 784 blocks
  conv3s_k<<<dim3(49, B_, SPL), 256, 0, stream>>>(h2e, h2t, w3e, w3t, b3e, b3t, part);
  // sum partials into xe / ltm
  reduce9_k<<<(RTOT + 255) / 256, 256, 0, stream>>>(part, xe, ltm);
  // patches + norms + log-temp means fused
  prep_k<<<dim3(N_, B_), 256, 0, stream>>>(xe, x, ltm, pe, yp, lt, sqv);
  // attention stage 1: weights
  attn_w_k<<<dim3((N_ + 3) / 4, B_), 256, 0, stream>>>(pe, lt, sqv, wkb);
  // attention stage 2: weighted neighbor sums
  attn_pv_k<<<dim3(N_, 4, B_), 256, 0, stream>>>(yp, wkb, nb);
  // fused fold + x passthrough
  constexpr int FT = B_ * CIN * (K_ + 1) * HW;
  foldcopy_k<<<(FT + 255) / 256, 256, 0, stream>>>(x, nb, out);
}

// Round 6
// 353.594 us; speedup vs baseline: 1.3948x; 1.0337x over previous
//
#include <hip/hip_runtime.h>
#include <math.h>

namespace {
constexpr int B_ = 2, CIN = 8, H_ = 224, W_ = 224;
constexpr int K_ = 7;
constexpr int F_ = 64, E_ = 8;
constexpr int N1 = 43, N2 = 43, N_ = N1 * N2;   // 1849
constexpr int M_ = 49;                           // candidates per query
constexpr int D_ = 800;                          // patch dim (C*P*P)
constexpr int HW = H_ * W_;

// workspace layout (floats).
constexpr size_t FHW = (size_t)B_ * F_ * HW;     // 6,422,528
constexpr size_t OFF_H1E = 0;                    // channels-last [b][h][w][64]
constexpr size_t OFF_H1T = OFF_H1E + FHW;
constexpr size_t OFF_H2E = OFF_H1T + FHW;        // NCHW
constexpr size_t OFF_H2T = OFF_H2E + FHW;
constexpr size_t OFF_WK  = 0;                                  // B*N*343
constexpr size_t OFF_NB  = 1280000;                            // > Wk end
constexpr size_t OFF_XE  = OFF_H2T + FHW;
constexpr size_t OFF_LTM = OFF_XE + (size_t)B_ * E_ * HW;
constexpr size_t OFF_PE  = OFF_LTM + (size_t)B_ * HW;
constexpr size_t OFF_YP  = OFF_PE + (size_t)B_ * N_ * D_;
constexpr size_t OFF_LT  = OFF_YP + (size_t)B_ * N_ * D_;
constexpr size_t OFF_SQ  = OFF_LT + (size_t)B_ * N_;
// conv weights (prepped bf16 hi/lo) overlap the xe region (consumed before
// reduce9 writes xe): (2*294912 + 2*12288) shorts = 307,200 floats < 802,816.
constexpr int WPREP_N = 294912;   // conv2: 2br * 2kcb * 9idx * 4wv * 64lane * 8j
constexpr int WPREP1_N = 12288;   // conv1: 2br * 3ky * 4wv * 64lane * 8j
constexpr int WPREP_TOT = WPREP_N + WPREP1_N;

// conv3 split partials live in the dead h1e/h1t region (conv2 inputs,
// consumed before conv3 runs): 8 * B * 9 * HW = 7,225,344 < 12,845,056.
constexpr int SPL = 8;                            // cin splits for conv3
constexpr int RTOT = B_ * 9 * HW;                 // 903,168 per split

__device__ __forceinline__ int clampi(int v, int lo, int hi) {
  return min(max(v, lo), hi);
}

typedef __attribute__((ext_vector_type(8))) short short8;
typedef __attribute__((ext_vector_type(4))) float float4v;
} // namespace

// ---------------------------------------------------------------------------
// Weight prep: conv2 (t < WPREP_N) and conv1 (rest) bf16 hi/lo splits.
// ---------------------------------------------------------------------------
__global__ __launch_bounds__(256) void wprep_k(
    const float* __restrict__ w_e, const float* __restrict__ w_t,
    const float* __restrict__ w1e, const float* __restrict__ w1t,
    unsigned short* __restrict__ whi, unsigned short* __restrict__ wlo,
    unsigned short* __restrict__ whi1, unsigned short* __restrict__ wlo1) {
  int t = blockIdx.x * 256 + threadIdx.x;
  if (t >= WPREP_TOT) return;
  float v;
  unsigned short* dh;
  unsigned short* dl;
  int di;
  if (t < WPREP_N) {
    int j = t & 7;
    int lane = (t >> 3) & 63;
    int wv = (t >> 9) & 3;
    int t2 = t >> 11;
    int idx = t2 % 9;
    int t3 = t2 / 9;
    int kcb = t3 & 1;
    int br = t3 >> 1;
    const float* wgt = br ? w_t : w_e;
    int co = wv * 16 + (lane & 15);
    int ci = kcb * 32 + 8 * (lane >> 4) + j;
    v = wgt[((size_t)co * 64 + ci) * 9 + idx];
    dh = whi; dl = wlo; di = t;
  } else {
    int t1 = t - WPREP_N;
    int j = t1 & 7;
    int lane = (t1 >> 3) & 63;
    int wv = (t1 >> 9) & 3;
    int t2 = t1 >> 11;
    int ky = t2 % 3;
    int br = t2 / 3;
    const float* wgt = br ? w1t : w1e;
    int co = wv * 16 + (lane & 15);
    int kx = lane >> 4;
    int ci = j;
    v = (kx < 3) ? wgt[(((size_t)co * 8 + ci) * 3 + ky) * 3 + kx] : 0.f;
    dh = whi1; dl = wlo1; di = t1;
  }
  unsigned u = __float_as_uint(v);
  unsigned short hi = (unsigned short)(u >> 16);
  float rem = v - __uint_as_float(u & 0xffff0000u);
  unsigned short lo = (unsigned short)(__float_as_uint(rem) >> 16);
  dh[di] = hi;
  dl[di] = lo;
}

// ---------------------------------------------------------------------------
// conv1 (8->64, relu) via MFMA bf16 3-term hi/lo split (unchanged from R12).
// ---------------------------------------------------------------------------
__global__ __launch_bounds__(256) void conv1_k(
    const float* __restrict__ x,
    const unsigned short* __restrict__ whi1, const unsigned short* __restrict__ wlo1,
    const float* __restrict__ b_e, float* __restrict__ o_e,
    const float* __restrict__ b_t, float* __restrict__ o_t) {
  const int tile = blockIdx.x;
  const int b = blockIdx.z & 1;
  const int br = blockIdx.z >> 1;
  const float* bias = br ? b_t : b_e;
  float* out = br ? o_t : o_e;

  const int th0 = (tile / 14) * 16, tw0 = (tile % 14) * 16;
  const int tid = threadIdx.x;
  const int wv = tid >> 6, lane = tid & 63;
  const int q = lane >> 4, n = lane & 15;

  __shared__ unsigned short sT[342 * 20];   // 18 rows x 19 cols x (8hi+8lo)

  const float* xB = x + (size_t)b * CIN * HW;
#pragma unroll
  for (int it = 0; it < 2; ++it) {
    int s = tid + 256 * it;
    if (s < 342) {
      int lr = s / 19, lc = s - lr * 19;
      int gh = th0 + lr - 1, gw = tw0 + lc - 1;
      short8 h8, l8;
#pragma unroll
      for (int ci = 0; ci < 8; ++ci) { h8[ci] = 0; l8[ci] = 0; }
      if (lc < 18 && gh >= 0 && gh < H_ && gw >= 0 && gw < W_) {
        const float* xp = xB + (size_t)gh * W_ + gw;
#pragma unroll
        for (int ci = 0; ci < 8; ++ci) {
          float v = xp[(size_t)ci * HW];
          unsigned u = __float_as_uint(v);
          float rem = v - __uint_as_float(u & 0xffff0000u);
          h8[ci] = (short)(u >> 16);
          l8[ci] = (short)(__float_as_uint(rem) >> 16);
        }
      }
      *(short8*)&sT[s * 20] = h8;
      *(short8*)&sT[s * 20 + 8] = l8;
    }
  }

  const short8* wh8 = (const short8*)whi1;
  const short8* wl8 = (const short8*)wlo1;
  short8 Ah[3], Al[3];
#pragma unroll
  for (int ky = 0; ky < 3; ++ky) {
    int ab = ((br * 3 + ky) * 4 + wv) * 64 + lane;
    Ah[ky] = wh8[ab];
    Al[ky] = wl8[ab];
  }

  float4v acc[16];
#pragma unroll
  for (int pr = 0; pr < 16; ++pr) acc[pr] = (float4v)0.f;

  __syncthreads();

#pragma unroll
  for (int r = 0; r < 18; ++r) {
    const unsigned short* p = &sT[(r * 19 + n + q) * 20];
    short8 Bh = *(const short8*)p;
    short8 Bl = *(const short8*)(p + 8);
#pragma unroll
    for (int ky = 0; ky < 3; ++ky) {
      const int pr = r - ky;
      if (pr >= 0 && pr < 16) {
        acc[pr] = __builtin_amdgcn_mfma_f32_16x16x32_bf16(Ah[ky], Bh, acc[pr], 0, 0, 0);
        acc[pr] = __builtin_amdgcn_mfma_f32_16x16x32_bf16(Al[ky], Bh, acc[pr], 0, 0, 0);
        acc[pr] = __builtin_amdgcn_mfma_f32_16x16x32_bf16(Ah[ky], Bl, acc[pr], 0, 0, 0);
      }
    }
  }

  float4v bv = *(const float4v*)&bias[wv * 16 + 4 * q];
#pragma unroll
  for (int pr = 0; pr < 16; ++pr) {
    float4v v;
#pragma unroll
    for (int r = 0; r < 4; ++r) v[r] = fmaxf(acc[pr][r] + bv[r], 0.f);
    *(float4v*)&out[(((size_t)b * H_ + th0 + pr) * W_ + tw0 + n) * 64 + wv * 16 + 4 * q] = v;
  }
}

// ---------------------------------------------------------------------------
// conv2 (64->64, relu) via MFMA bf16 3-term hi/lo split.
// R13: staging restructured — po[21]+mask precomputed once; per kcb all 21
// float2 loads issued back-to-back into registers (one vmcnt drain) before
// the convert+ds_write pass. R12 paid ~600cy global latency 21x serially per
// kcb per wave. Numerics identical.
// ---------------------------------------------------------------------------
__global__ __launch_bounds__(256) void conv2_mfma_k(
    const float* __restrict__ in_e, const float* __restrict__ in_t,
    const unsigned short* __restrict__ whi, const unsigned short* __restrict__ wlo,
    const float* __restrict__ b_e, const float* __restrict__ b_t,
    float* __restrict__ out_e, float* __restrict__ out_t) {
  constexpr int NLD = 21;                       // ceil(5184/256)
  const int tile = blockIdx.x;
  const int b = blockIdx.z & 1;
  const int br = blockIdx.z >> 1;
  const float* in = br ? in_t : in_e;
  const float* bias = br ? b_t : b_e;
  float* out = br ? out_t : out_e;

  const int th0 = (tile / 14) * 16, tw0 = (tile % 14) * 16;
  const int tid = threadIdx.x;
  const int wv = tid >> 6, lane = tid & 63;
  const int q = lane >> 4, n = lane & 15;

  __shared__ unsigned short sT[18 * 18 * 72];
  unsigned* sT32 = (unsigned*)sT;

  float4v acc[16];
#pragma unroll
  for (int pr = 0; pr < 16; ++pr) acc[pr] = (float4v)0.f;

  const float* inB = in + (size_t)b * HW * 64;
  const short8* whi8 = (const short8*)whi;
  const short8* wlo8 = (const short8*)wlo;

  // precompute staging addresses + in-bounds mask (kcb-independent)
  int po[NLD];
  unsigned okm = 0;
#pragma unroll
  for (int j = 0; j < NLD; ++j) {
    int s = tid + 256 * j;
    int sp = s >> 4, cp = s & 15;
    int lr = sp / 18, lc = sp - lr * 18;
    int gh = th0 + lr - 1, gw = tw0 + lc - 1;
    bool ok = (s < 5184) && gh >= 0 && gh < H_ && gw >= 0 && gw < W_;
    po[j] = ok ? (gh * W_ + gw) * 64 + 2 * cp : 0;
    if (ok) okm |= (1u << j);
  }

  for (int kcb = 0; kcb < 2; ++kcb) {
    // batched loads: all 21 issued independently, single drain
    float2 stg[NLD];
#pragma unroll
    for (int j = 0; j < NLD; ++j)
      stg[j] = *(const float2*)&inB[(size_t)po[j] + kcb * 32];

    __syncthreads();   // previous kcb's LDS fully consumed
#pragma unroll
    for (int j = 0; j < NLD; ++j) {
      int s = tid + 256 * j;
      if (s < 5184) {
        int sp = s >> 4, cp = s & 15;
        bool ok = (okm >> j) & 1;
        float vx = ok ? stg[j].x : 0.f;
        float vy = ok ? stg[j].y : 0.f;
        unsigned u0 = __float_as_uint(vx), u1 = __float_as_uint(vy);
        float r0 = vx - __uint_as_float(u0 & 0xffff0000u);
        float r1 = vy - __uint_as_float(u1 & 0xffff0000u);
        unsigned l0 = __float_as_uint(r0) >> 16, l1 = __float_as_uint(r1) >> 16;
        sT32[sp * 36 + cp] = (u0 >> 16) | ((u1 >> 16) << 16);
        sT32[sp * 36 + 16 + cp] = l0 | (l1 << 16);
      }
    }
    __syncthreads();

    short8 Ah[9], Al[9];
    const int abase = (((br * 2 + kcb) * 9) * 4 + wv) * 64 + lane;
#pragma unroll
    for (int idx = 0; idx < 9; ++idx) {
      Ah[idx] = whi8[abase + idx * 256];
      Al[idx] = wlo8[abase + idx * 256];
    }

#pragma unroll
    for (int r = 0; r < 18; ++r) {
      short8 Bh[3], Bl[3];
#pragma unroll
      for (int kx = 0; kx < 3; ++kx) {
        const unsigned short* p = &sT[(r * 18 + n + kx) * 72 + 8 * q];
        Bh[kx] = *(const short8*)p;
        Bl[kx] = *(const short8*)(p + 32);
      }
#pragma unroll
      for (int ky = 0; ky < 3; ++ky) {
        const int pr = r - ky;
        if (pr >= 0 && pr < 16) {
#pragma unroll
          for (int kx = 0; kx < 3; ++kx) {
            const int idx = ky * 3 + kx;
            acc[pr] = __builtin_amdgcn_mfma_f32_16x16x32_bf16(Ah[idx], Bh[kx], acc[pr], 0, 0, 0);
            acc[pr] = __builtin_amdgcn_mfma_f32_16x16x32_bf16(Al[idx], Bh[kx], acc[pr], 0, 0, 0);
            acc[pr] = __builtin_amdgcn_mfma_f32_16x16x32_bf16(Ah[idx], Bl[kx], acc[pr], 0, 0, 0);
          }
        }
      }
    }
  }

  float4v bv = *(const float4v*)&bias[wv * 16 + 4 * q];
#pragma unroll
  for (int pr = 0; pr < 16; ++pr) {
#pragma unroll
    for (int r = 0; r < 4; ++r) {
      int co = wv * 16 + 4 * q + r;
      float v = fmaxf(acc[pr][r] + bv[r], 0.f);
      out[((size_t)b * 64 + co) * HW + (th0 + pr) * W_ + tw0 + n] = v;
    }
  }
}

// ---------------------------------------------------------------------------
// conv3 e+t merged, cin split 8 ways (grid z), 32x32 tile, 4 rows/thread,
// CIB=2, weights via wave-uniform global reads. (unchanged)
// ---------------------------------------------------------------------------
__global__ __launch_bounds__(256) void conv3s_k(
    const float* __restrict__ h2e, const float* __restrict__ h2t,
    const float* __restrict__ w3e, const float* __restrict__ w3t,
    const float* __restrict__ b3e, const float* __restrict__ b3t,
    float* __restrict__ part) {
  constexpr int CIB = 2;
  constexpr int TR = 34, TC = 34;             // padded tile 34 x 34
  constexpr int PLN = TR * TC;                // 1156
  constexpr int NST = 2 * CIB * PLN;          // 4624 (both branches)
  constexpr int NLD = (NST + 255) / 256;      // 19

  const int tile = blockIdx.x;                // 0..48 (7 x 7)
  const int b = blockIdx.y;
  const int sp = blockIdx.z;                  // cin split 0..7
  const int cin0 = sp * 8;
  const int th0 = (tile / 7) * 32, tw0 = (tile % 7) * 32;
  const int tid = threadIdx.x;
  const int tx = tid & 31, ty = tid >> 5;     // 4 rows per thread

  __shared__ float sT[2][CIB][PLN];           // 18496 B

  int po[NLD];
  unsigned okm = 0;
#pragma unroll
  for (int j = 0; j < NLD; ++j) {
    int s = tid + 256 * j;
    int rem2 = s % (CIB * PLN);
    int pl = rem2 / PLN, rem = rem2 % PLN;
    int lr = rem / TC, lc = rem - lr * TC;
    int gh = th0 + lr - 1, gw = tw0 + lc - 1;
    bool ok = (s < NST) && gh >= 0 && gh < H_ && gw >= 0 && gw < W_;
    po[j] = ok ? (pl * HW + gh * W_ + gw) : 0;
    if (ok) okm |= (1u << j);
  }

  const float* heB = h2e + ((size_t)b * 64 + cin0) * HW;
  const float* htB = h2t + ((size_t)b * 64 + cin0) * HW;

  float stg[NLD];
#pragma unroll
  for (int j = 0; j < NLD; ++j) {
    int s = tid + 256 * j;
    const float* src = (s < CIB * PLN) ? heB : htB;
    float v = src[po[j]];
    stg[j] = ((okm >> j) & 1) ? v : 0.f;
  }

  float acc[9][4];
#pragma unroll
  for (int c = 0; c < 9; ++c) {
    float bv = (sp == 0) ? ((c < 8) ? b3e[c] : b3t[0]) : 0.f;
#pragma unroll
    for (int dy = 0; dy < 4; ++dy) acc[c][dy] = bv;
  }

  for (int cb = 0; cb < 8; cb += CIB) {
    __syncthreads();
#pragma unroll
    for (int j = 0; j < NLD; ++j) {
      int s = tid + 256 * j;
      if (s < NST) ((float*)sT)[s] = stg[j];
    }
    __syncthreads();
    if (cb + CIB < 8) {
      const size_t off = (size_t)(cb + CIB) * HW;
#pragma unroll
      for (int j = 0; j < NLD; ++j) {
        int s = tid + 256 * j;
        const float* src = (s < CIB * PLN) ? (heB + off) : (htB + off);
        float v = src[po[j]];
        stg[j] = ((okm >> j) & 1) ? v : 0.f;
      }
    }
#pragma unroll
    for (int ci = 0; ci < CIB; ++ci) {
      const int cin = cin0 + cb + ci;
      float ive[6][3], ivt[6][3];
#pragma unroll
      for (int r = 0; r < 6; ++r)
#pragma unroll
        for (int s2 = 0; s2 < 3; ++s2) {
          ive[r][s2] = sT[0][ci][(4 * ty + r) * TC + tx + s2];
          ivt[r][s2] = sT[1][ci][(4 * ty + r) * TC + tx + s2];
        }
#pragma unroll
      for (int c = 0; c < 9; ++c) {
        // wave-uniform global weight reads -> scalar loads
        const float* wp = (c < 8) ? &w3e[((size_t)c * 64 + cin) * 9]
                                  : &w3t[(size_t)cin * 9];
        const float (*iv)[3] = (c < 8) ? ive : ivt;
#pragma unroll
        for (int dy = 0; dy < 4; ++dy) {
          acc[c][dy] += iv[dy + 0][0] * wp[0] + iv[dy + 0][1] * wp[1] +
                        iv[dy + 0][2] * wp[2] + iv[dy + 1][0] * wp[3] +
                        iv[dy + 1][1] * wp[4] + iv[dy + 1][2] * wp[5] +
                        iv[dy + 2][0] * wp[6] + iv[dy + 2][1] * wp[7] +
                        iv[dy + 2][2] * wp[8];
        }
      }
    }
  }

  float* pB = part + (size_t)sp * RTOT + (size_t)b * 9 * HW;
#pragma unroll
  for (int dy = 0; dy < 4; ++dy) {
    const int h = th0 + 4 * ty + dy, w = tw0 + tx;
#pragma unroll
    for (int c = 0; c < 9; ++c)
      pB[(size_t)c * HW + h * W_ + w] = acc[c][dy];
  }
}

// ---------------------------------------------------------------------------
// reduce the 8 conv3 partials into xe (c<8) and ltm (c==8).
// ---------------------------------------------------------------------------
__global__ __launch_bounds__(256) void reduce9_k(const float* __restrict__ part,
                                                 float* __restrict__ xe,
                                                 float* __restrict__ ltm) {
  int i = blockIdx.x * 256 + threadIdx.x;
  if (i >= RTOT) return;
  float s = 0.f;
#pragma unroll
  for (int sp = 0; sp < SPL; ++sp) s += part[(size_t)sp * RTOT + i];
  int p = i % HW;
  int c = (i / HW) % 9;
  int b = i / (9 * HW);
  if (c < 8)
    xe[((size_t)(b * 8 + c)) * HW + p] = s;
  else
    ltm[(size_t)b * HW + p] = s;
}

// ---------------------------------------------------------------------------
// prep: per (b,n) block (256 thr): write pe row (from xe), yp row (from x),
// reduce sq = ||pe||^2 and lt = mean of 10x10 ltm patch. (unchanged)
// ---------------------------------------------------------------------------
__global__ __launch_bounds__(256) void prep_k(const float* __restrict__ xe,
                                              const float* __restrict__ x,
                                              const float* __restrict__ ltm,
                                              float* __restrict__ pe,
                                              float* __restrict__ yp,
                                              float* __restrict__ lt,
                                              float* __restrict__ sq) {
  const int n = blockIdx.x, b = blockIdx.y;
  const int tid = threadIdx.x;
  const int wv = tid >> 6, lane = tid & 63;
  const int q1 = n / N2, q2 = n % N2;
  const int r0 = q1 * 5, c0 = q2 * 5;

  float s = 0.f;
  float* peR = pe + ((size_t)b * N_ + n) * D_;
  float* ypR = yp + ((size_t)b * N_ + n) * D_;
#pragma unroll
  for (int j = 0; j < 4; ++j) {
    int d = tid + 256 * j;
    if (d < D_) {
      int c = d / 100;
      int rr = (d / 10) % 10;
      int cc = d % 10;
      size_t si = ((size_t)(b * 8 + c) * H_ + r0 + rr) * W_ + c0 + cc;
      float ve = xe[si];
      float vx = x[si];
      peR[d] = ve;
      ypR[d] = vx;
      s += ve * ve;
    }
  }
  float t = 0.f;
  if (tid < 100) t = ltm[(size_t)b * HW + (r0 + tid / 10) * W_ + c0 + tid % 10];

#pragma unroll
  for (int off = 32; off > 0; off >>= 1) {
    s += __shfl_xor(s, off);
    t += __shfl_xor(t, off);
  }
  __shared__ float rs[4], rt[4];
  if (lane == 0) { rs[wv] = s; rt[wv] = t; }
  __syncthreads();
  if (tid == 0) {
    sq[b * N_ + n] = rs[0] + rs[1] + rs[2] + rs[3];
    lt[b * N_ + n] = (rt[0] + rt[1] + rt[2] + rt[3]) * 0.01f;
  }
}

// ---------------------------------------------------------------------------
// attn stage 1 (unchanged).
// ---------------------------------------------------------------------------
__global__ __launch_bounds__(256) void attn_w_k(const float* __restrict__ pe,
                                                const float* __restrict__ lt,
                                                const float* __restrict__ sq,
                                                float* __restrict__ wk) {
  const int wv = threadIdx.x >> 6, lane = threadIdx.x & 63;
  const int n = blockIdx.x * 4 + wv;
  if (n >= N_) return;
  const int b = blockIdx.y;
  const int q1 = n / N2, q2 = n % N2;

  const float* peB = pe + (size_t)b * N_ * D_;
  const float* qrow = peB + (size_t)n * D_;
  float q[13];
#pragma unroll
  for (int t = 0; t < 13; ++t) {
    int s = t * 64 + lane;
    q[t] = (s < D_) ? qrow[s] : 0.f;
  }

  const float sqn = sq[b * N_ + n];
  const float itemp = expf(-lt[b * N_ + n]);
  float gm = -INFINITY;

  for (int o1 = 0; o1 < 7; ++o1) {
    int c1 = clampi(q1 + o1 - 3, 0, N1 - 1);
    const float* rowb = peB + (size_t)(c1 * N2) * D_;
#pragma unroll
    for (int o2 = 0; o2 < 7; ++o2) {
      int c2 = clampi(q2 + o2 - 3, 0, N2 - 1);
      int cn = c1 * N2 + c2;
      const float* crow = rowb + (size_t)c2 * D_;
      float a = 0.f;
#pragma unroll
      for (int t = 0; t < 13; ++t) {
        float v;
        if (t < 12) v = crow[t * 64 + lane];
        else v = (lane < 32) ? crow[768 + lane] : 0.f;
        a += q[t] * v;
      }
#pragma unroll
      for (int off = 32; off > 0; off >>= 1) a += __shfl_xor(a, off);
      float Dv = -(sqn + sq[b * N_ + cn] - 2.f * a);
      float lg = (cn == n) ? -1e9f : Dv * itemp;
      const int m = o1 * 7 + o2;
      gm = (lane == m) ? lg : gm;
    }
  }

  float cur = (lane < M_) ? gm : -INFINITY;
  float* wrow = wk + (size_t)(b * N_ + n) * (M_ * K_);
#pragma unroll
  for (int k = 0; k < K_; ++k) {
    float mx = cur;
#pragma unroll
    for (int off = 32; off > 0; off >>= 1) mx = fmaxf(mx, __shfl_xor(mx, off));
    float e = (lane < M_) ? expf(cur - mx) : 0.f;
    float ssum = e;
#pragma unroll
    for (int off = 32; off > 0; off >>= 1) ssum += __shfl_xor(ssum, off);
    float w = e / ssum;
    if (lane < M_) wrow[lane * K_ + k] = w;
    cur += log1pf(-fminf(w, 1.f - 1e-6f));
  }
}

// ---------------------------------------------------------------------------
// attn stage 2 (unchanged).
// ---------------------------------------------------------------------------
__global__ __launch_bounds__(256) void attn_pv_k(const float* __restrict__ yp,
                                                 const float* __restrict__ wk,
                                                 float* __restrict__ nb) {
  const int wv = threadIdx.x >> 6, lane = threadIdx.x & 63;
  const int n = blockIdx.x;
  const int b = blockIdx.z;
  const int sl = blockIdx.y * 4 + wv;
  const int d = sl * 64 + lane;
  if (d >= D_) return;
  const int q1 = n / N2, q2 = n % N2;

  const float* ypB = yp + (size_t)b * N_ * D_;
  const float* wrow = wk + (size_t)(b * N_ + n) * (M_ * K_);

  float acc[K_];
#pragma unroll
  for (int k = 0; k < K_; ++k) acc[k] = 0.f;

#pragma unroll
  for (int o1 = 0; o1 < 7; ++o1) {
    int c1 = clampi(q1 + o1 - 3, 0, N1 - 1);
#pragma unroll
    for (int o2 = 0; o2 < 7; ++o2) {
      int c2 = clampi(q2 + o2 - 3, 0, N2 - 1);
      int cn = c1 * N2 + c2;
      float y = ypB[(size_t)cn * D_ + d];
      const int m = o1 * 7 + o2;
#pragma unroll
      for (int k = 0; k < K_; ++k) acc[k] += wrow[m * K_ + k] * y;
    }
  }
#pragma unroll
  for (int k = 0; k < K_; ++k)
    nb[(((size_t)k * B_ + b) * N_ + n) * D_ + d] = acc[k];
}

// ---------------------------------------------------------------------------
// Fused output: channels 0..7 copy x; channels 8..63 fold-gather from nb.
// ---------------------------------------------------------------------------
__global__ __launch_bounds__(256) void foldcopy_k(const float* __restrict__ x,
                                                  const float* __restrict__ nb,
                                                  float* __restrict__ out) {
  int i = blockIdx.x * 256 + threadIdx.x;
  constexpr int CT = CIN * (K_ + 1);  // 64
  constexpr int TOT = B_ * CT * HW;
  if (i >= TOT) return;
  int w = i % W_;
  int h = (i / W_) % H_;
  int c64 = (i / HW) % CT;
  int b = i / (HW * CT);
  if (c64 < CIN) {
    out[i] = x[((size_t)b * CIN + c64) * HW + h * W_ + w];
    return;
  }
  int k = (c64 - CIN) >> 3, c = (c64 - CIN) & 7;
  int q1lo = max(0, (h - 5) / 5), q1hi = min(N1 - 1, h / 5);
  int q2lo = max(0, (w - 5) / 5), q2hi = min(N2 - 1, w / 5);
  float val = 0.f;
  int cnt = 0;
  for (int q1 = q1lo; q1 <= q1hi; ++q1)
    for (int q2 = q2lo; q2 <= q2hi; ++q2) {
      int i0 = h - 5 * q1, j0 = w - 5 * q2;
      int nn = q1 * N2 + q2;
      val += nb[(((size_t)k * B_ + b) * N_ + nn) * D_ + c * 100 + i0 * 10 + j0];
      ++cnt;
    }
  out[i] = (cnt > 0) ? val / (float)cnt : 0.f;
}

extern "C" void kernel_launch(void* const* d_in, const int* in_sizes, int n_in,
                              void* d_out, int out_size, void* d_ws,
                              size_t ws_size, hipStream_t stream) {
  const float* x   = (const float*)d_in[0];
  const float* w1e = (const float*)d_in[1];
  const float* b1e = (const float*)d_in[2];
  const float* w2e = (const float*)d_in[3];
  const float* b2e = (const float*)d_in[4];
  const float* w3e = (const float*)d_in[5];
  const float* b3e = (const float*)d_in[6];
  const float* w1t = (const float*)d_in[7];
  const float* b1t = (const float*)d_in[8];
  const float* w2t = (const float*)d_in[9];
  const float* b2t = (const float*)d_in[10];
  const float* w3t = (const float*)d_in[11];
  const float* b3t = (const float*)d_in[12];

  float* ws  = (float*)d_ws;
  float* out = (float*)d_out;

  float* h1e = ws + OFF_H1E;   // channels-last
  float* h1t = ws + OFF_H1T;   // channels-last
  float* h2e = ws + OFF_H2E;   // NCHW
  float* h2t = ws + OFF_H2T;   // NCHW
  float* wkb = ws + OFF_WK;
  float* nb  = ws + OFF_NB;
  float* xe  = ws + OFF_XE;
  float* ltm = ws + OFF_LTM;
  float* pe  = ws + OFF_PE;
  float* yp  = ws + OFF_YP;
  float* lt  = ws + OFF_LT;
  float* sqv = ws + OFF_SQ;
  unsigned short* whi  = (unsigned short*)(ws + OFF_XE);  // consumed before xe written
  unsigned short* wlo  = whi + WPREP_N;
  unsigned short* whi1 = wlo + WPREP_N;
  unsigned short* wlo1 = whi1 + WPREP1_N;
  float* part = ws + OFF_H1E;  // conv3 partials over dead h1 region

  // weight prep (conv1 + conv2)
  wprep_k<<<(WPREP_TOT + 255) / 256, 256, 0, stream>>>(w2e, w2t, w1e, w1t,
                                                       whi, wlo, whi1, wlo1);
  // conv1 (8 -> 64, relu) via MFMA, channels-last output
  conv1_k<<<dim3(196, 1, 4), 256, 0, stream>>>(x, whi1, wlo1, b1e, h1e, b1t, h1t);
  // conv2 (64 -> 64, relu) via MFMA, both branches + batches in one dispatch
  conv2_mfma_k<<<dim3(196, 1, 4), 256, 0, stream>>>(h1e, h1t, whi, wlo, b2e, b2t, h2e, h2t);
  // conv3 (64 -> 8 + 64 -> 1) merged, cin split 8 ways -> 784 blocks
  conv3s_k<<<dim3(49, B_, SPL), 256, 0, stream>>>(h2e, h2t, w3e, w3t, b3e, b3t, part);
  // sum partials into xe / ltm
  reduce9_k<<<(RTOT + 255) / 256, 256, 0, stream>>>(part, xe, ltm);
  // patches + norms + log-temp means fused
  prep_k<<<dim3(N_, B_), 256, 0, stream>>>(xe, x, ltm, pe, yp, lt, sqv);
  // attention stage 1: weights
  attn_w_k<<<dim3((N_ + 3) / 4, B_), 256, 0, stream>>>(pe, lt, sqv, wkb);
  // attention stage 2: weighted neighbor sums
  attn_pv_k<<<dim3(N_, 4, B_), 256, 0, stream>>>(yp, wkb, nb);
  // fused fold + x passthrough
  constexpr int FT = B_ * CIN * (K_ + 1) * HW;
  foldcopy_k<<<(FT + 255) / 256, 256, 0, stream>>>(x, nb, out);
}

// Round 7
// 324.098 us; speedup vs baseline: 1.5217x; 1.0910x over previous
//
#include <hip/hip_runtime.h>
#include <math.h>

namespace {
constexpr int B_ = 2, CIN = 8, H_ = 224, W_ = 224;
constexpr int K_ = 7;
constexpr int F_ = 64, E_ = 8;
constexpr int N1 = 43, N2 = 43, N_ = N1 * N2;   // 1849
constexpr int M_ = 49;                           // candidates per query
constexpr int D_ = 800;                          // patch dim (C*P*P)
constexpr int HW = H_ * W_;

// workspace layout (floats).
constexpr size_t FHW = (size_t)B_ * F_ * HW;     // 6,422,528
constexpr size_t OFF_H1E = 0;                    // channels-last [b][h][w][64]
constexpr size_t OFF_H1T = OFF_H1E + FHW;
constexpr size_t OFF_H2E = OFF_H1T + FHW;        // channels-last bf16 hi/lo
constexpr size_t OFF_H2T = OFF_H2E + FHW;
constexpr size_t OFF_WK  = 0;                                  // B*N*343
constexpr size_t OFF_NB  = 1280000;                            // > Wk end
constexpr size_t OFF_XE  = OFF_H2T + FHW;
constexpr size_t OFF_LTM = OFF_XE + (size_t)B_ * E_ * HW;
constexpr size_t OFF_PE  = OFF_LTM + (size_t)B_ * HW;
constexpr size_t OFF_YP  = OFF_PE + (size_t)B_ * N_ * D_;
constexpr size_t OFF_LT  = OFF_YP + (size_t)B_ * N_ * D_;
constexpr size_t OFF_SQ  = OFF_LT + (size_t)B_ * N_;
// conv1/conv2 prepped weights overlap the xe region (consumed by conv1/conv2,
// which run before conv3 writes xe): 614,400 ushorts = 307,200 fl < 802,816.
// conv3 prepped weights live in the pe region (prep_k writes pe AFTER conv3).
constexpr int WPREP_N = 294912;   // conv2: 2br * 2kcb * 9idx * 4wv * 64lane * 8j
constexpr int WPREP1_N = 12288;   // conv1: 2br * 3ky * 4wv * 64lane * 8j
constexpr int WPREP3_N = 9216;    // conv3 per-set: 2kcb * 9idx * 64lane * 8j
constexpr int WPREP_TOT = WPREP_N + WPREP1_N + 2 * WPREP3_N;

__device__ __forceinline__ int clampi(int v, int lo, int hi) {
  return min(max(v, lo), hi);
}

// bijective XCD-chunk swizzle (m204): consecutive same-XCD blocks get
// contiguous work indices -> neighbor queries share an XCD L2.
__device__ __forceinline__ int xcd_swz(int x, int nwg) {
  int xcd = x & 7, idx = x >> 3;
  int q = nwg >> 3, r = nwg & 7;
  int base = (xcd < r) ? xcd * (q + 1) : r * (q + 1) + (xcd - r) * q;
  return base + idx;
}

typedef __attribute__((ext_vector_type(8))) short short8;
typedef __attribute__((ext_vector_type(4))) float float4v;
typedef __attribute__((ext_vector_type(4))) unsigned short ushort4v;
} // namespace

// ---------------------------------------------------------------------------
// Weight prep: conv2, conv1, conv3(e), conv3(t) bf16 hi/lo splits.
// ---------------------------------------------------------------------------
__global__ __launch_bounds__(256) void wprep_k(
    const float* __restrict__ w_e, const float* __restrict__ w_t,
    const float* __restrict__ w1e, const float* __restrict__ w1t,
    const float* __restrict__ w3e, const float* __restrict__ w3t,
    unsigned short* __restrict__ whi, unsigned short* __restrict__ wlo,
    unsigned short* __restrict__ whi1, unsigned short* __restrict__ wlo1,
    unsigned short* __restrict__ whi3, unsigned short* __restrict__ wlo3) {
  int t = blockIdx.x * 256 + threadIdx.x;
  if (t >= WPREP_TOT) return;
  float v;
  unsigned short* dh;
  unsigned short* dl;
  int di;
  if (t < WPREP_N) {
    int j = t & 7;
    int lane = (t >> 3) & 63;
    int wv = (t >> 9) & 3;
    int t2 = t >> 11;
    int idx = t2 % 9;
    int t3 = t2 / 9;
    int kcb = t3 & 1;
    int br = t3 >> 1;
    const float* wgt = br ? w_t : w_e;
    int co = wv * 16 + (lane & 15);
    int ci = kcb * 32 + 8 * (lane >> 4) + j;
    v = wgt[((size_t)co * 64 + ci) * 9 + idx];
    dh = whi; dl = wlo; di = t;
  } else if (t < WPREP_N + WPREP1_N) {
    int t1 = t - WPREP_N;
    int j = t1 & 7;
    int lane = (t1 >> 3) & 63;
    int wv = (t1 >> 9) & 3;
    int t2 = t1 >> 11;
    int ky = t2 % 3;
    int br = t2 / 3;
    const float* wgt = br ? w1t : w1e;
    int co = wv * 16 + (lane & 15);
    int kx = lane >> 4;
    int ci = j;
    v = (kx < 3) ? wgt[(((size_t)co * 8 + ci) * 3 + ky) * 3 + kx] : 0.f;
    dh = whi1; dl = wlo1; di = t1;
  } else {
    int t3v = t - WPREP_N - WPREP1_N;          // [0, 2*9216)
    int set = t3v / WPREP3_N;                   // 0 = e, 1 = t
    int rem = t3v - set * WPREP3_N;
    int j = rem & 7;
    int lane = (rem >> 3) & 63;
    int t2 = rem >> 9;                          // 0..17
    int idx = t2 % 9;
    int kcb = t2 / 9;
    int co = lane & 15;
    int ci = kcb * 32 + 8 * (lane >> 4) + j;
    if (set == 0)
      v = (co < 8) ? w3e[((size_t)co * 64 + ci) * 9 + idx] : 0.f;
    else
      v = (co == 0) ? w3t[(size_t)ci * 9 + idx] : 0.f;
    dh = whi3; dl = wlo3; di = t3v;
  }
  unsigned u = __float_as_uint(v);
  unsigned short hi = (unsigned short)(u >> 16);
  float rem = v - __uint_as_float(u & 0xffff0000u);
  unsigned short lo = (unsigned short)(__float_as_uint(rem) >> 16);
  dh[di] = hi;
  dl[di] = lo;
}

// ---------------------------------------------------------------------------
// conv1 (8->64, relu) via MFMA bf16 3-term hi/lo split (unchanged).
// ---------------------------------------------------------------------------
__global__ __launch_bounds__(256) void conv1_k(
    const float* __restrict__ x,
    const unsigned short* __restrict__ whi1, const unsigned short* __restrict__ wlo1,
    const float* __restrict__ b_e, float* __restrict__ o_e,
    const float* __restrict__ b_t, float* __restrict__ o_t) {
  const int tile = blockIdx.x;
  const int b = blockIdx.z & 1;
  const int br = blockIdx.z >> 1;
  const float* bias = br ? b_t : b_e;
  float* out = br ? o_t : o_e;

  const int th0 = (tile / 14) * 16, tw0 = (tile % 14) * 16;
  const int tid = threadIdx.x;
  const int wv = tid >> 6, lane = tid & 63;
  const int q = lane >> 4, n = lane & 15;

  __shared__ unsigned short sT[342 * 20];   // 18 rows x 19 cols x (8hi+8lo)

  const float* xB = x + (size_t)b * CIN * HW;
#pragma unroll
  for (int it = 0; it < 2; ++it) {
    int s = tid + 256 * it;
    if (s < 342) {
      int lr = s / 19, lc = s - lr * 19;
      int gh = th0 + lr - 1, gw = tw0 + lc - 1;
      short8 h8, l8;
#pragma unroll
      for (int ci = 0; ci < 8; ++ci) { h8[ci] = 0; l8[ci] = 0; }
      if (lc < 18 && gh >= 0 && gh < H_ && gw >= 0 && gw < W_) {
        const float* xp = xB + (size_t)gh * W_ + gw;
#pragma unroll
        for (int ci = 0; ci < 8; ++ci) {
          float v = xp[(size_t)ci * HW];
          unsigned u = __float_as_uint(v);
          float rem = v - __uint_as_float(u & 0xffff0000u);
          h8[ci] = (short)(u >> 16);
          l8[ci] = (short)(__float_as_uint(rem) >> 16);
        }
      }
      *(short8*)&sT[s * 20] = h8;
      *(short8*)&sT[s * 20 + 8] = l8;
    }
  }

  const short8* wh8 = (const short8*)whi1;
  const short8* wl8 = (const short8*)wlo1;
  short8 Ah[3], Al[3];
#pragma unroll
  for (int ky = 0; ky < 3; ++ky) {
    int ab = ((br * 3 + ky) * 4 + wv) * 64 + lane;
    Ah[ky] = wh8[ab];
    Al[ky] = wl8[ab];
  }

  float4v acc[16];
#pragma unroll
  for (int pr = 0; pr < 16; ++pr) acc[pr] = (float4v)0.f;

  __syncthreads();

#pragma unroll
  for (int r = 0; r < 18; ++r) {
    const unsigned short* p = &sT[(r * 19 + n + q) * 20];
    short8 Bh = *(const short8*)p;
    short8 Bl = *(const short8*)(p + 8);
#pragma unroll
    for (int ky = 0; ky < 3; ++ky) {
      const int pr = r - ky;
      if (pr >= 0 && pr < 16) {
        acc[pr] = __builtin_amdgcn_mfma_f32_16x16x32_bf16(Ah[ky], Bh, acc[pr], 0, 0, 0);
        acc[pr] = __builtin_amdgcn_mfma_f32_16x16x32_bf16(Al[ky], Bh, acc[pr], 0, 0, 0);
        acc[pr] = __builtin_amdgcn_mfma_f32_16x16x32_bf16(Ah[ky], Bl, acc[pr], 0, 0, 0);
      }
    }
  }

  float4v bv = *(const float4v*)&bias[wv * 16 + 4 * q];
#pragma unroll
  for (int pr = 0; pr < 16; ++pr) {
    float4v v;
#pragma unroll
    for (int r = 0; r < 4; ++r) v[r] = fmaxf(acc[pr][r] + bv[r], 0.f);
    *(float4v*)&out[(((size_t)b * H_ + th0 + pr) * W_ + tw0 + n) * 64 + wv * 16 + 4 * q] = v;
  }
}

// ---------------------------------------------------------------------------
// conv2 (64->64, relu) via MFMA. R14: epilogue converts to bf16 hi/lo and
// stores CHANNELS-LAST via an LDS store-transpose (two 8-row halves,
// [128px][68] padded), so conv3 can consume it with MFMA and no conversion.
// hi/lo store == the exact conversion conv3 staging would apply to fp32.
// ---------------------------------------------------------------------------
__global__ __launch_bounds__(256) void conv2_mfma_k(
    const float* __restrict__ in_e, const float* __restrict__ in_t,
    const unsigned short* __restrict__ whi, const unsigned short* __restrict__ wlo,
    const float* __restrict__ b_e, const float* __restrict__ b_t,
    unsigned short* __restrict__ ehi, unsigned short* __restrict__ elo,
    unsigned short* __restrict__ thi, unsigned short* __restrict__ tlo) {
  constexpr int NLD = 21;                       // ceil(5184/256)
  const int tile = blockIdx.x;
  const int b = blockIdx.z & 1;
  const int br = blockIdx.z >> 1;
  const float* in = br ? in_t : in_e;
  const float* bias = br ? b_t : b_e;
  unsigned short* ohi = br ? thi : ehi;
  unsigned short* olo = br ? tlo : elo;

  const int th0 = (tile / 14) * 16, tw0 = (tile % 14) * 16;
  const int tid = threadIdx.x;
  const int wv = tid >> 6, lane = tid & 63;
  const int q = lane >> 4, n = lane & 15;

  __shared__ unsigned short sT[18 * 18 * 72];
  unsigned* sT32 = (unsigned*)sT;

  float4v acc[16];
#pragma unroll
  for (int pr = 0; pr < 16; ++pr) acc[pr] = (float4v)0.f;

  const float* inB = in + (size_t)b * HW * 64;
  const short8* whi8 = (const short8*)whi;
  const short8* wlo8 = (const short8*)wlo;

  int po[NLD];
  unsigned okm = 0;
#pragma unroll
  for (int j = 0; j < NLD; ++j) {
    int s = tid + 256 * j;
    int sp = s >> 4, cp = s & 15;
    int lr = sp / 18, lc = sp - lr * 18;
    int gh = th0 + lr - 1, gw = tw0 + lc - 1;
    bool ok = (s < 5184) && gh >= 0 && gh < H_ && gw >= 0 && gw < W_;
    po[j] = ok ? (gh * W_ + gw) * 64 + 2 * cp : 0;
    if (ok) okm |= (1u << j);
  }

  for (int kcb = 0; kcb < 2; ++kcb) {
    float2 stg[NLD];
#pragma unroll
    for (int j = 0; j < NLD; ++j)
      stg[j] = *(const float2*)&inB[(size_t)po[j] + kcb * 32];

    __syncthreads();
#pragma unroll
    for (int j = 0; j < NLD; ++j) {
      int s = tid + 256 * j;
      if (s < 5184) {
        int sp = s >> 4, cp = s & 15;
        bool ok = (okm >> j) & 1;
        float vx = ok ? stg[j].x : 0.f;
        float vy = ok ? stg[j].y : 0.f;
        unsigned u0 = __float_as_uint(vx), u1 = __float_as_uint(vy);
        float r0 = vx - __uint_as_float(u0 & 0xffff0000u);
        float r1 = vy - __uint_as_float(u1 & 0xffff0000u);
        unsigned l0 = __float_as_uint(r0) >> 16, l1 = __float_as_uint(r1) >> 16;
        sT32[sp * 36 + cp] = (u0 >> 16) | ((u1 >> 16) << 16);
        sT32[sp * 36 + 16 + cp] = l0 | (l1 << 16);
      }
    }
    __syncthreads();

    short8 Ah[9], Al[9];
    const int abase = (((br * 2 + kcb) * 9) * 4 + wv) * 64 + lane;
#pragma unroll
    for (int idx = 0; idx < 9; ++idx) {
      Ah[idx] = whi8[abase + idx * 256];
      Al[idx] = wlo8[abase + idx * 256];
    }

#pragma unroll
    for (int r = 0; r < 18; ++r) {
      short8 Bh[3], Bl[3];
#pragma unroll
      for (int kx = 0; kx < 3; ++kx) {
        const unsigned short* p = &sT[(r * 18 + n + kx) * 72 + 8 * q];
        Bh[kx] = *(const short8*)p;
        Bl[kx] = *(const short8*)(p + 32);
      }
#pragma unroll
      for (int ky = 0; ky < 3; ++ky) {
        const int pr = r - ky;
        if (pr >= 0 && pr < 16) {
#pragma unroll
          for (int kx = 0; kx < 3; ++kx) {
            const int idx = ky * 3 + kx;
            acc[pr] = __builtin_amdgcn_mfma_f32_16x16x32_bf16(Ah[idx], Bh[kx], acc[pr], 0, 0, 0);
            acc[pr] = __builtin_amdgcn_mfma_f32_16x16x32_bf16(Al[idx], Bh[kx], acc[pr], 0, 0, 0);
            acc[pr] = __builtin_amdgcn_mfma_f32_16x16x32_bf16(Ah[idx], Bl[kx], acc[pr], 0, 0, 0);
          }
        }
      }
    }
  }

  // ---- epilogue: bias+relu -> hi/lo, LDS transpose, dense stores ----
  float4v bv = *(const float4v*)&bias[wv * 16 + 4 * q];
  unsigned short* sHi = (unsigned short*)sT;     // [128][68]
  unsigned short* sLo = sHi + 128 * 68;
  __syncthreads();                               // all sT MFMA reads done
#pragma unroll
  for (int hf = 0; hf < 2; ++hf) {
#pragma unroll
    for (int pr8 = 0; pr8 < 8; ++pr8) {
      int pr = hf * 8 + pr8;
      int px = pr8 * 16 + n;
      ushort4v hv, lv;
#pragma unroll
      for (int r = 0; r < 4; ++r) {
        float v = fmaxf(acc[pr][r] + bv[r], 0.f);
        unsigned u = __float_as_uint(v);
        float rem = v - __uint_as_float(u & 0xffff0000u);
        hv[r] = (unsigned short)(u >> 16);
        lv[r] = (unsigned short)(__float_as_uint(rem) >> 16);
      }
      *(ushort4v*)&sHi[px * 68 + wv * 16 + 4 * q] = hv;
      *(ushort4v*)&sLo[px * 68 + wv * 16 + 4 * q] = lv;
    }
    __syncthreads();
#pragma unroll
    for (int i = 0; i < 4; ++i) {
      int f = tid + 256 * i;
      int px = f >> 3, c8 = f & 7;
      int h = th0 + hf * 8 + (px >> 4), w = tw0 + (px & 15);
      size_t o = ((size_t)(b * H_ + h) * W_ + w) * 64 + c8 * 8;
      *(short8*)&ohi[o] = *(const short8*)&sHi[px * 68 + c8 * 8];
      *(short8*)&olo[o] = *(const short8*)&sLo[px * 68 + c8 * 8];
    }
    __syncthreads();
  }
}

// ---------------------------------------------------------------------------
// conv3 via MFMA (R14). 8x16 px tile, 4 waves x 2 rows, branch+batch in
// grid z (1568 blocks). Reads channels-last hi/lo h2, stages 10x18 px tile,
// K=(ci,kx) packed like conv2, ky via acc-row shift. e-branch -> xe (8 co),
// t-branch -> ltm (1 co). Replaces conv3s + reduce9 (and their 56MB of
// partial traffic).
// ---------------------------------------------------------------------------
__global__ __launch_bounds__(256) void conv3_mfma_k(
    const unsigned short* __restrict__ h2ehi, const unsigned short* __restrict__ h2elo,
    const unsigned short* __restrict__ h2thi, const unsigned short* __restrict__ h2tlo,
    const unsigned short* __restrict__ whi3, const unsigned short* __restrict__ wlo3,
    const float* __restrict__ b3e, const float* __restrict__ b3t,
    float* __restrict__ xe, float* __restrict__ ltm) {
  constexpr int NLD = 12;                       // ceil(2880/256)
  const int tile = blockIdx.x;                  // 28 x 14
  const int b = blockIdx.z & 1;
  const int br = blockIdx.z >> 1;
  const unsigned short* ihi = (br ? h2thi : h2ehi) + (size_t)b * HW * 64;
  const unsigned short* ilo = (br ? h2tlo : h2elo) + (size_t)b * HW * 64;

  const int th0 = (tile / 14) * 8, tw0 = (tile % 14) * 16;
  const int tid = threadIdx.x;
  const int wv = tid >> 6, lane = tid & 63;
  const int q = lane >> 4, n = lane & 15;

  __shared__ unsigned short sT[180 * 72];       // 10x18 px, 25920 B
  unsigned* sT32 = (unsigned*)sT;

  int po[NLD];
  unsigned okm = 0;
#pragma unroll
  for (int j = 0; j < NLD; ++j) {
    int s = tid + 256 * j;
    int sp = s >> 4, cp = s & 15;
    int lr = sp / 18, lc = sp - lr * 18;
    int gh = th0 + lr - 1, gw = tw0 + lc - 1;
    bool ok = (s < 2880) && gh >= 0 && gh < H_ && gw >= 0 && gw < W_;
    po[j] = ok ? (gh * W_ + gw) * 64 + 2 * cp : 0;
    if (ok) okm |= (1u << j);
  }

  const short8* wh8 = (const short8*)whi3;
  const short8* wl8 = (const short8*)wlo3;
  const int brBase = br * 1152;                 // set stride in short8 units

  float4v acc[2];
  acc[0] = (float4v)0.f;
  acc[1] = (float4v)0.f;

  for (int kcb = 0; kcb < 2; ++kcb) {
    unsigned sgh[NLD], sgl[NLD];
#pragma unroll
    for (int j = 0; j < NLD; ++j) {
      sgh[j] = *(const unsigned*)&ihi[(size_t)po[j] + kcb * 32];
      sgl[j] = *(const unsigned*)&ilo[(size_t)po[j] + kcb * 32];
    }
    __syncthreads();
#pragma unroll
    for (int j = 0; j < NLD; ++j) {
      int s = tid + 256 * j;
      if (s < 2880) {
        int sp = s >> 4, cp = s & 15;
        bool ok = (okm >> j) & 1;
        sT32[sp * 36 + cp] = ok ? sgh[j] : 0u;
        sT32[sp * 36 + 16 + cp] = ok ? sgl[j] : 0u;
      }
    }
    __syncthreads();

    short8 Ah[9], Al[9];
#pragma unroll
    for (int idx = 0; idx < 9; ++idx) {
      int fe = brBase + (kcb * 9 + idx) * 64 + lane;
      Ah[idx] = wh8[fe];
      Al[idx] = wl8[fe];
    }

#pragma unroll
    for (int r = 0; r < 4; ++r) {
      const int rr = 2 * wv + r;
      short8 Bh[3], Bl[3];
#pragma unroll
      for (int kx = 0; kx < 3; ++kx) {
        const unsigned short* p = &sT[(rr * 18 + n + kx) * 72 + 8 * q];
        Bh[kx] = *(const short8*)p;
        Bl[kx] = *(const short8*)(p + 32);
      }
#pragma unroll
      for (int ky = 0; ky < 3; ++ky) {
        const int pl = r - ky;
        if (pl >= 0 && pl < 2) {
#pragma unroll
          for (int kx = 0; kx < 3; ++kx) {
            const int idx = ky * 3 + kx;
            acc[pl] = __builtin_amdgcn_mfma_f32_16x16x32_bf16(Ah[idx], Bh[kx], acc[pl], 0, 0, 0);
            acc[pl] = __builtin_amdgcn_mfma_f32_16x16x32_bf16(Al[idx], Bh[kx], acc[pl], 0, 0, 0);
            acc[pl] = __builtin_amdgcn_mfma_f32_16x16x32_bf16(Ah[idx], Bl[kx], acc[pl], 0, 0, 0);
          }
        }
      }
    }
  }

  if (br == 0) {
    if (q < 2) {                                // co = 4q+r in [0,8)
      float4v bv = *(const float4v*)&b3e[4 * q];
#pragma unroll
      for (int pl = 0; pl < 2; ++pl) {
        int h = th0 + 2 * wv + pl;
#pragma unroll
        for (int r = 0; r < 4; ++r)
          xe[((size_t)(b * 8 + 4 * q + r) * H_ + h) * W_ + tw0 + n] = acc[pl][r] + bv[r];
      }
    }
  } else {
    if (q == 0) {                               // co 0 = log_temp
      float bt = b3t[0];
#pragma unroll
      for (int pl = 0; pl < 2; ++pl) {
        int h = th0 + 2 * wv + pl;
        ltm[(size_t)b * HW + h * W_ + tw0 + n] = acc[pl][0] + bt;
      }
    }
  }
}

// ---------------------------------------------------------------------------
// prep (unchanged).
// ---------------------------------------------------------------------------
__global__ __launch_bounds__(256) void prep_k(const float* __restrict__ xe,
                                              const float* __restrict__ x,
                                              const float* __restrict__ ltm,
                                              float* __restrict__ pe,
                                              float* __restrict__ yp,
                                              float* __restrict__ lt,
                                              float* __restrict__ sq) {
  const int n = blockIdx.x, b = blockIdx.y;
  const int tid = threadIdx.x;
  const int wv = tid >> 6, lane = tid & 63;
  const int q1 = n / N2, q2 = n % N2;
  const int r0 = q1 * 5, c0 = q2 * 5;

  float s = 0.f;
  float* peR = pe + ((size_t)b * N_ + n) * D_;
  float* ypR = yp + ((size_t)b * N_ + n) * D_;
#pragma unroll
  for (int j = 0; j < 4; ++j) {
    int d = tid + 256 * j;
    if (d < D_) {
      int c = d / 100;
      int rr = (d / 10) % 10;
      int cc = d % 10;
      size_t si = ((size_t)(b * 8 + c) * H_ + r0 + rr) * W_ + c0 + cc;
      float ve = xe[si];
      float vx = x[si];
      peR[d] = ve;
      ypR[d] = vx;
      s += ve * ve;
    }
  }
  float t = 0.f;
  if (tid < 100) t = ltm[(size_t)b * HW + (r0 + tid / 10) * W_ + c0 + tid % 10];

#pragma unroll
  for (int off = 32; off > 0; off >>= 1) {
    s += __shfl_xor(s, off);
    t += __shfl_xor(t, off);
  }
  __shared__ float rs[4], rt[4];
  if (lane == 0) { rs[wv] = s; rt[wv] = t; }
  __syncthreads();
  if (tid == 0) {
    sq[b * N_ + n] = rs[0] + rs[1] + rs[2] + rs[3];
    lt[b * N_ + n] = (rt[0] + rt[1] + rt[2] + rt[3]) * 0.01f;
  }
}

// ---------------------------------------------------------------------------
// attn stage 1. R14: XCD swizzle on the n-group (neighbor queries share L2).
// ---------------------------------------------------------------------------
__global__ __launch_bounds__(256) void attn_w_k(const float* __restrict__ pe,
                                                const float* __restrict__ lt,
                                                const float* __restrict__ sq,
                                                float* __restrict__ wk) {
  const int wv = threadIdx.x >> 6, lane = threadIdx.x & 63;
  const int ng = xcd_swz(blockIdx.x, (N_ + 3) / 4);
  const int n = ng * 4 + wv;
  if (n >= N_) return;
  const int b = blockIdx.y;
  const int q1 = n / N2, q2 = n % N2;

  const float* peB = pe + (size_t)b * N_ * D_;
  const float* qrow = peB + (size_t)n * D_;
  float q[13];
#pragma unroll
  for (int t = 0; t < 13; ++t) {
    int s = t * 64 + lane;
    q[t] = (s < D_) ? qrow[s] : 0.f;
  }

  const float sqn = sq[b * N_ + n];
  const float itemp = expf(-lt[b * N_ + n]);
  float gm = -INFINITY;

  for (int o1 = 0; o1 < 7; ++o1) {
    int c1 = clampi(q1 + o1 - 3, 0, N1 - 1);
    const float* rowb = peB + (size_t)(c1 * N2) * D_;
#pragma unroll
    for (int o2 = 0; o2 < 7; ++o2) {
      int c2 = clampi(q2 + o2 - 3, 0, N2 - 1);
      int cn = c1 * N2 + c2;
      const float* crow = rowb + (size_t)c2 * D_;
      float a = 0.f;
#pragma unroll
      for (int t = 0; t < 13; ++t) {
        float v;
        if (t < 12) v = crow[t * 64 + lane];
        else v = (lane < 32) ? crow[768 + lane] : 0.f;
        a += q[t] * v;
      }
#pragma unroll
      for (int off = 32; off > 0; off >>= 1) a += __shfl_xor(a, off);
      float Dv = -(sqn + sq[b * N_ + cn] - 2.f * a);
      float lg = (cn == n) ? -1e9f : Dv * itemp;
      const int m = o1 * 7 + o2;
      gm = (lane == m) ? lg : gm;
    }
  }

  float cur = (lane < M_) ? gm : -INFINITY;
  float* wrow = wk + (size_t)(b * N_ + n) * (M_ * K_);
#pragma unroll
  for (int k = 0; k < K_; ++k) {
    float mx = cur;
#pragma unroll
    for (int off = 32; off > 0; off >>= 1) mx = fmaxf(mx, __shfl_xor(mx, off));
    float e = (lane < M_) ? expf(cur - mx) : 0.f;
    float ssum = e;
#pragma unroll
    for (int off = 32; off > 0; off >>= 1) ssum += __shfl_xor(ssum, off);
    float w = e / ssum;
    if (lane < M_) wrow[lane * K_ + k] = w;
    cur += log1pf(-fminf(w, 1.f - 1e-6f));
  }
}

// ---------------------------------------------------------------------------
// attn stage 2. R14: XCD swizzle on n + hoisted c2*D offsets.
// ---------------------------------------------------------------------------
__global__ __launch_bounds__(256) void attn_pv_k(const float* __restrict__ yp,
                                                 const float* __restrict__ wk,
                                                 float* __restrict__ nb) {
  const int wv = threadIdx.x >> 6, lane = threadIdx.x & 63;
  const int n = xcd_swz(blockIdx.x, N_);
  const int b = blockIdx.z;
  const int sl = blockIdx.y * 4 + wv;
  const int d = sl * 64 + lane;
  if (d >= D_) return;
  const int q1 = n / N2, q2 = n % N2;

  const float* ypB = yp + (size_t)b * N_ * D_;
  const float* wrow = wk + (size_t)(b * N_ + n) * (M_ * K_);

  int c2D[7];
#pragma unroll
  for (int o2 = 0; o2 < 7; ++o2)
    c2D[o2] = clampi(q2 + o2 - 3, 0, N2 - 1) * D_;

  float acc[K_];
#pragma unroll
  for (int k = 0; k < K_; ++k) acc[k] = 0.f;

#pragma unroll
  for (int o1 = 0; o1 < 7; ++o1) {
    int c1 = clampi(q1 + o1 - 3, 0, N1 - 1);
    const float* rb = ypB + (size_t)(c1 * N2) * D_ + d;
#pragma unroll
    for (int o2 = 0; o2 < 7; ++o2) {
      float y = rb[c2D[o2]];
      const int m = o1 * 7 + o2;
#pragma unroll
      for (int k = 0; k < K_; ++k) acc[k] += wrow[m * K_ + k] * y;
    }
  }
#pragma unroll
  for (int k = 0; k < K_; ++k)
    nb[(((size_t)k * B_ + b) * N_ + n) * D_ + d] = acc[k];
}

// ---------------------------------------------------------------------------
// Fused output: channels 0..7 copy x; channels 8..63 fold-gather from nb.
// ---------------------------------------------------------------------------
__global__ __launch_bounds__(256) void foldcopy_k(const float* __restrict__ x,
                                                  const float* __restrict__ nb,
                                                  float* __restrict__ out) {
  int i = blockIdx.x * 256 + threadIdx.x;
  constexpr int CT = CIN * (K_ + 1);  // 64
  constexpr int TOT = B_ * CT * HW;
  if (i >= TOT) return;
  int w = i % W_;
  int h = (i / W_) % H_;
  int c64 = (i / HW) % CT;
  int b = i / (HW * CT);
  if (c64 < CIN) {
    out[i] = x[((size_t)b * CIN + c64) * HW + h * W_ + w];
    return;
  }
  int k = (c64 - CIN) >> 3, c = (c64 - CIN) & 7;
  int q1lo = max(0, (h - 5) / 5), q1hi = min(N1 - 1, h / 5);
  int q2lo = max(0, (w - 5) / 5), q2hi = min(N2 - 1, w / 5);
  float val = 0.f;
  int cnt = 0;
  for (int q1 = q1lo; q1 <= q1hi; ++q1)
    for (int q2 = q2lo; q2 <= q2hi; ++q2) {
      int i0 = h - 5 * q1, j0 = w - 5 * q2;
      int nn = q1 * N2 + q2;
      val += nb[(((size_t)k * B_ + b) * N_ + nn) * D_ + c * 100 + i0 * 10 + j0];
      ++cnt;
    }
  out[i] = (cnt > 0) ? val / (float)cnt : 0.f;
}

extern "C" void kernel_launch(void* const* d_in, const int* in_sizes, int n_in,
                              void* d_out, int out_size, void* d_ws,
                              size_t ws_size, hipStream_t stream) {
  const float* x   = (const float*)d_in[0];
  const float* w1e = (const float*)d_in[1];
  const float* b1e = (const float*)d_in[2];
  const float* w2e = (const float*)d_in[3];
  const float* b2e = (const float*)d_in[4];
  const float* w3e = (const float*)d_in[5];
  const float* b3e = (const float*)d_in[6];
  const float* w1t = (const float*)d_in[7];
  const float* b1t = (const float*)d_in[8];
  const float* w2t = (const float*)d_in[9];
  const float* b2t = (const float*)d_in[10];
  const float* w3t = (const float*)d_in[11];
  const float* b3t = (const float*)d_in[12];

  float* ws  = (float*)d_ws;
  float* out = (float*)d_out;

  float* h1e = ws + OFF_H1E;   // channels-last fp32
  float* h1t = ws + OFF_H1T;
  unsigned short* h2ehi = (unsigned short*)(ws + OFF_H2E);   // channels-last hi/lo
  unsigned short* h2elo = h2ehi + (size_t)B_ * HW * 64;
  unsigned short* h2thi = (unsigned short*)(ws + OFF_H2T);
  unsigned short* h2tlo = h2thi + (size_t)B_ * HW * 64;
  float* wkb = ws + OFF_WK;
  float* nb  = ws + OFF_NB;
  float* xe  = ws + OFF_XE;
  float* ltm = ws + OFF_LTM;
  float* pe  = ws + OFF_PE;
  float* yp  = ws + OFF_YP;
  float* lt  = ws + OFF_LT;
  float* sqv = ws + OFF_SQ;
  unsigned short* whi  = (unsigned short*)(ws + OFF_XE);  // consumed before xe written
  unsigned short* wlo  = whi + WPREP_N;
  unsigned short* whi1 = wlo + WPREP_N;
  unsigned short* wlo1 = whi1 + WPREP1_N;
  unsigned short* whi3 = (unsigned short*)(ws + OFF_PE);  // consumed before pe written
  unsigned short* wlo3 = whi3 + 2 * WPREP3_N;

  // weight prep (conv1 + conv2 + conv3)
  wprep_k<<<(WPREP_TOT + 255) / 256, 256, 0, stream>>>(
      w2e, w2t, w1e, w1t, w3e, w3t, whi, wlo, whi1, wlo1, whi3, wlo3);
  // conv1 (8 -> 64, relu) via MFMA, channels-last output
  conv1_k<<<dim3(196, 1, 4), 256, 0, stream>>>(x, whi1, wlo1, b1e, h1e, b1t, h1t);
  // conv2 (64 -> 64, relu) via MFMA -> channels-last bf16 hi/lo
  conv2_mfma_k<<<dim3(196, 1, 4), 256, 0, stream>>>(h1e, h1t, whi, wlo, b2e, b2t,
                                                    h2ehi, h2elo, h2thi, h2tlo);
  // conv3 (64 -> 8 / 64 -> 1) via MFMA, 8x16 tiles, branch+batch in z
  conv3_mfma_k<<<dim3(392, 1, 4), 256, 0, stream>>>(h2ehi, h2elo, h2thi, h2tlo,
                                                    whi3, wlo3, b3e, b3t, xe, ltm);
  // patches + norms + log-temp means fused
  prep_k<<<dim3(N_, B_), 256, 0, stream>>>(xe, x, ltm, pe, yp, lt, sqv);
  // attention stage 1: weights
  attn_w_k<<<dim3((N_ + 3) / 4, B_), 256, 0, stream>>>(pe, lt, sqv, wkb);
  // attention stage 2: weighted neighbor sums
  attn_pv_k<<<dim3(N_, 4, B_), 256, 0, stream>>>(yp, wkb, nb);
  // fused fold + x passthrough
  constexpr int FT = B_ * CIN * (K_ + 1) * HW;
  foldcopy_k<<<(FT + 255) / 256, 256, 0, stream>>>(x, nb, out);
}